// Round 15
// baseline (609.963 us; speedup 1.0000x reference)
//
#include <hip/hip_runtime.h>
#include <cstddef>

typedef __attribute__((ext_vector_type(8))) short bf16x8;
typedef __attribute__((ext_vector_type(4))) short bf16x4;
typedef __attribute__((ext_vector_type(4))) float f32x4;

constexpr int Bc = 64;
constexpr int Sc = 200;
constexpr int Hc = 4;
constexpr int Dc = 256;
constexpr int HDc = 64;
constexpr int NPc = Bc * Sc;          // 12800 rows
constexpr int NPROJ = 15;
constexpr int NWT   = 17;             // 15 proj weights + Wd + Wda
constexpr int NBH   = Bc * Hc;        // 256
constexpr float SCALE = 0.125f;       // 1/sqrt(64)

// proj indices
// 0 iq, 1 ik, 2 iv, 3 pq, 4 pk, 5 aq, 6 ak, 7 haq, 8 hak, 9 hav,
// 10 iqc, 11 ciq, 12 cqp, 13 cqp_a, 14 pqc
// 13 score channels in natural order (9-set then 4-set):
__constant__ int c_QPall[13] = {0,10,0,11,5,12,3,14,3, 7,13,14,3};
__constant__ int c_KPall[13] = {1,6,4,1,6,4,1,6,4, 8,4,8,4};

__device__ __forceinline__ short f2bf(float x) {
    union { float f; unsigned u; } v; v.f = x;
    unsigned r = v.u + 0x7FFFu + ((v.u >> 16) & 1u);
    return (short)(r >> 16);
}
__device__ __forceinline__ float bf2f(short x) {
    union { unsigned u; float f; } v; v.u = ((unsigned)(unsigned short)x) << 16;
    return v.f;
}
__device__ __forceinline__ unsigned cvtpk(float lo, float hi) {
    unsigned r;
    asm("v_cvt_pk_bf16_f32 %0, %1, %2" : "=v"(r) : "v"(lo), "v"(hi));
    return r;
}
__device__ __forceinline__ f32x4 mfma16(bf16x8 a, bf16x8 b, f32x4 c) {
    return __builtin_amdgcn_mfma_f32_16x16x32_bf16(a, b, c, 0, 0, 0);
}

struct ProjArgsM {
    const short* A[NPROJ];
    const float* bias[NPROJ];
};
struct WList { const float* w[NWT]; };

// ---------------------------------------------------------------------------
// prep: cast_in (blocks 0..12799) + cast_wt (12800..13071) + wf1t (13072..13267)
// ---------------------------------------------------------------------------
__global__ __launch_bounds__(256) void prep_kernel(
    const float* __restrict__ X, const float* __restrict__ AT,
    const float* __restrict__ P, const float* __restrict__ HA,
    short* __restrict__ inb,
    WList wl, short* __restrict__ WTall,
    const float* __restrict__ Wf1, short* __restrict__ WTf1)
{
    __shared__ float tbuf[64][65];
    const int bid = blockIdx.x;
    const int tid = threadIdx.x;

    if (bid < 12800) {
        int ten = bid / 3200, blk = bid - ten * 3200;
        const float* srcs[4] = {X, AT, P, HA};
        const float* src = srcs[ten];
        short* d = inb + (size_t)ten * NPc * Dc;
        int t = blk * 256 + tid;
        float4 v = ((const float4*)src)[t];
        uint2 st;
        st.x = cvtpk(v.x, v.y);
        st.y = cvtpk(v.z, v.w);
        *(uint2*)(d + (size_t)t * 4) = st;
    } else if (bid < 13072) {
        int q = bid - 12800;
        int p = q >> 4, tile = q & 15;
        int k0 = (tile >> 2) * 64, n0 = (tile & 3) * 64;
        const float* W = wl.w[p];
        short* d = WTall + (size_t)p * Dc * Dc;
        for (int i = tid; i < 64 * 64; i += 256) {
            int k = i >> 6, n = i & 63;
            tbuf[k][n] = W[(size_t)(k0 + k) * Dc + n0 + n];
        }
        __syncthreads();
        for (int i = tid; i < 64 * 64; i += 256) {
            int n = i >> 6, k = i & 63;
            d[(size_t)(n0 + n) * Dc + k0 + k] = f2bf(tbuf[k][n]);
        }
    } else {
        int t = (bid - 13072) * 256 + tid;
        if (t < 224 * 224) {
            int j = t / 224, i = t % 224;
            WTf1[t] = (i < Sc && j < Sc) ? f2bf(Wf1[(size_t)i * Sc + j]) : (short)0;
        }
    }
}

// ---------------------------------------------------------------------------
// V transpose: proj_bf[p={2,9}] head strips -> vt[t][(b*4+h)][64][224] bf16
// (cols 200..223 zeroed)
// ---------------------------------------------------------------------------
__global__ __launch_bounds__(256) void vt_kernel(const short* __restrict__ proj_bf,
                                                 short* __restrict__ vt) {
    const int bid = blockIdx.x;
    const int t  = bid >> 8;
    const int bh = bid & 255;
    const int b = bh >> 2, h = bh & 3;
    const int p = t ? 9 : 2;
    const short* src = proj_bf + ((size_t)p * NPc + (size_t)b * Sc) * Dc + h * HDc;
    short* dst = vt + ((size_t)t * NBH + bh) * 64 * 224;
    __shared__ short tile[200][72];
    const int tid = threadIdx.x;
    for (int idx = tid; idx < 200 * 8; idx += 256) {
        int j = idx >> 3, c8 = idx & 7;
        *(bf16x8*)(&tile[j][c8 * 8]) = *(const bf16x8*)(src + (size_t)j * Dc + c8 * 8);
    }
    __syncthreads();
    for (int idx = tid; idx < 64 * 28; idx += 256) {
        int d = idx / 28, c8 = idx % 28;
        bf16x8 o;
        #pragma unroll
        for (int i = 0; i < 8; ++i) {
            int j = c8 * 8 + i;
            o[i] = (j < 200) ? tile[j][d] : (short)0;
        }
        *(bf16x8*)(dst + (size_t)d * 224 + c8 * 8) = o;
    }
}

// ---------------------------------------------------------------------------
// Kernel 1 (MFMA): all 15 projections. C[64 x 256] tile per block. bf16 out.
// ---------------------------------------------------------------------------
__global__ __launch_bounds__(256, 4) void proj_mfma(
    ProjArgsM args, const short* __restrict__ WTall, short* __restrict__ proj_bf)
{
    const int p  = blockIdx.y;
    const int m0 = blockIdx.x * 64;
    const short* __restrict__ A   = args.A[p];
    const short* __restrict__ WTp = WTall + (size_t)p * Dc * Dc;
    const float* __restrict__ bias = args.bias[p];
    short* __restrict__ ob = proj_bf + (size_t)p * NPc * Dc;

    __shared__ __align__(16) short As[64 * 264];
    const int tid = threadIdx.x;
    const int lane = tid & 63, w = tid >> 6;
    const int l15 = lane & 15, l4 = lane >> 4;

    for (int t = tid; t < 64 * 32; t += 256) {
        int r = t >> 5, c8 = t & 31;
        *(bf16x8*)(As + r * 264 + c8 * 8) = *(const bf16x8*)(A + (size_t)(m0 + r) * Dc + c8 * 8);
    }
    __syncthreads();

    f32x4 acc[4][4];
    #pragma unroll
    for (int mi = 0; mi < 4; ++mi)
        #pragma unroll
        for (int ni = 0; ni < 4; ++ni) acc[mi][ni] = (f32x4){};

    const int nb = w * 64;
    #pragma unroll
    for (int ks = 0; ks < 8; ++ks) {
        bf16x8 bfr[4];
        #pragma unroll
        for (int ni = 0; ni < 4; ++ni)
            bfr[ni] = *(const bf16x8*)(WTp + (size_t)(nb + ni * 16 + l15) * Dc + ks * 32 + l4 * 8);
        #pragma unroll
        for (int mi = 0; mi < 4; ++mi) {
            bf16x8 a = *(const bf16x8*)(As + (mi * 16 + l15) * 264 + ks * 32 + l4 * 8);
            #pragma unroll
            for (int ni = 0; ni < 4; ++ni)
                acc[mi][ni] = mfma16(a, bfr[ni], acc[mi][ni]);
        }
    }

    float bv[4];
    #pragma unroll
    for (int ni = 0; ni < 4; ++ni) bv[ni] = bias[nb + ni * 16 + l15];
    #pragma unroll
    for (int mi = 0; mi < 4; ++mi) {
        #pragma unroll
        for (int ni = 0; ni < 4; ++ni) {
            int n = nb + ni * 16 + l15;
            int m = m0 + mi * 16 + l4 * 4;
            unsigned p01 = cvtpk(acc[mi][ni][0] + bv[ni], acc[mi][ni][1] + bv[ni]);
            unsigned p23 = cvtpk(acc[mi][ni][2] + bv[ni], acc[mi][ni][3] + bv[ni]);
            ob[(size_t)(m + 0) * Dc + n] = (short)p01;
            ob[(size_t)(m + 1) * Dc + n] = (short)(p01 >> 16);
            ob[(size_t)(m + 2) * Dc + n] = (short)p23;
            ob[(size_t)(m + 3) * Dc + n] = (short)(p23 >> 16);
        }
    }
}

// ---------------------------------------------------------------------------
// Kernel A (scores): S[bhl][c][m][j] = fw_c * (q_m . k_j), bf16, pad zeroed.
// grid (13, nbh), 256 threads. Q panel in LDS; K via L2.
// ---------------------------------------------------------------------------
__global__ __launch_bounds__(256) void scores_kernel(
    const short* __restrict__ proj_bf,
    const float* __restrict__ fw9, const float* __restrict__ fw4,
    short* __restrict__ S, int bh0)
{
    const int c   = blockIdx.x;         // channel 0..12
    const int bhl = blockIdx.y;
    const int bh  = bh0 + bhl;
    const int b = bh >> 2, h = bh & 3;
    const int tid = threadIdx.x;
    const int lane = tid & 63, wv = tid >> 6;
    const int l15 = lane & 15, l4 = lane >> 4;

    const float fwv = (c < 9) ? fw9[c] : fw4[c - 9];
    short* Sbase = S + (size_t)(bhl * 13 + c) * Sc * 224;

    __shared__ __align__(16) short Ql[208 * 68];
    const short* Qb = proj_bf + ((size_t)c_QPall[c] * NPc + (size_t)b * Sc) * Dc + h * HDc;
    for (int t = tid; t < 200 * 8; t += 256) {
        int r = t >> 3, c8 = t & 7;
        *(bf16x8*)(Ql + r * 68 + c8 * 8) = *(const bf16x8*)(Qb + (size_t)r * Dc + c8 * 8);
    }
    {   // zero Ql pad rows 200..207 (MFMA A-fragment hygiene)
        bf16x8 z = {};
        for (int t = tid; t < 8 * 8; t += 256) {
            int r = 200 + (t >> 3), c8 = t & 7;
            *(bf16x8*)(Ql + r * 68 + c8 * 8) = z;
        }
    }
    {   // zero S pad cols 200..223
        bf16x8 z = {};
        for (int t = tid; t < 600; t += 256) {
            int r = t / 3, c8 = t % 3;
            *(bf16x8*)(Sbase + (size_t)r * 224 + 200 + c8 * 8) = z;
        }
    }
    __syncthreads();

    const short* Kb = proj_bf + ((size_t)c_KPall[c] * NPc + (size_t)b * Sc) * Dc + h * HDc;
    for (int jt = wv; jt < 13; jt += 4) {
        const int j = jt * 16 + l15;             // may reach 207: stays inside proj_bf
        bf16x8 k0 = *(const bf16x8*)(Kb + (size_t)j * Dc + l4 * 8);
        bf16x8 k1 = *(const bf16x8*)(Kb + (size_t)j * Dc + 32 + l4 * 8);
        #pragma unroll
        for (int mt = 0; mt < 13; ++mt) {
            f32x4 acc = {};
            bf16x8 a0 = *(const bf16x8*)(Ql + (mt * 16 + l15) * 68 + l4 * 8);
            bf16x8 a1 = *(const bf16x8*)(Ql + (mt * 16 + l15) * 68 + 32 + l4 * 8);
            acc = mfma16(a0, k0, acc);
            acc = mfma16(a1, k1, acc);
            int mrow = mt * 16 + l4 * 4;
            if (j < Sc && mrow < Sc) {
                unsigned p01 = cvtpk(acc[0] * fwv, acc[1] * fwv);
                unsigned p23 = cvtpk(acc[2] * fwv, acc[3] * fwv);
                Sbase[(size_t)(mrow + 0) * 224 + j] = (short)p01;
                Sbase[(size_t)(mrow + 1) * 224 + j] = (short)(p01 >> 16);
                Sbase[(size_t)(mrow + 2) * 224 + j] = (short)p23;
                Sbase[(size_t)(mrow + 3) * 224 + j] = (short)(p23 >> 16);
            }
        }
    }
}

// ---------------------------------------------------------------------------
// Kernel B (gate GEMM): e[m] = sum_j relu( (S@Wf1)[m][j] + bf1[j] ) * Wf2[j]
// M-space uniform: rows of S chunk [nbh*13*200][224]. 128-row tiles.
// ---------------------------------------------------------------------------
__global__ __launch_bounds__(256) void gate_kernel(
    const short* __restrict__ S,
    const short* __restrict__ WT,        // [224][224] bf16 (Wf1^T, 0-pad)
    const float* __restrict__ bf1,
    const float* __restrict__ Wf2,
    float* __restrict__ e)               // chunk-offset pointer
{
    const int r0 = blockIdx.x * 128;
    const int tid = threadIdx.x;
    const int lane = tid & 63, wv = tid >> 6;
    const int l15 = lane & 15, l4 = lane >> 4;

    __shared__ __align__(16) short Sl[128 * 232];
    __shared__ float evw[4 * 128];
    __shared__ float bf1l[224];
    __shared__ float wf2l[224];

    for (int t = tid; t < 128 * 28; t += 256) {
        int r = t / 28, c8 = t % 28;
        *(bf16x8*)(Sl + r * 232 + c8 * 8) = *(const bf16x8*)(S + (size_t)(r0 + r) * 224 + c8 * 8);
    }
    if (tid < 224) {
        bf1l[tid] = (tid < Sc) ? bf1[tid] : 0.f;
        wf2l[tid] = (tid < Sc) ? Wf2[tid] : 0.f;
    }
    __syncthreads();

    float epart[8];
    #pragma unroll
    for (int mt = 0; mt < 8; ++mt) epart[mt] = 0.f;

    for (int nt = wv; nt < 14; nt += 4) {
        const int jr = nt * 16 + l15;
        bf16x8 wfrag[7];
        #pragma unroll
        for (int ks = 0; ks < 7; ++ks)
            wfrag[ks] = *(const bf16x8*)(WT + (size_t)jr * 224 + ks * 32 + l4 * 8);
        f32x4 cg[8];
        #pragma unroll
        for (int mt = 0; mt < 8; ++mt) cg[mt] = (f32x4){};
        #pragma unroll
        for (int ks = 0; ks < 7; ++ks) {
            #pragma unroll
            for (int mt = 0; mt < 8; ++mt) {
                bf16x8 bb = *(const bf16x8*)(Sl + (mt * 16 + l15) * 232 + ks * 32 + l4 * 8);
                cg[mt] = mfma16(wfrag[ks], bb, cg[mt]);
            }
        }
        float4 b1 = *(const float4*)(bf1l + nt * 16 + l4 * 4);
        float4 w2 = *(const float4*)(wf2l + nt * 16 + l4 * 4);
        #pragma unroll
        for (int mt = 0; mt < 8; ++mt) {
            float s = fmaxf(cg[mt][0] + b1.x, 0.f) * w2.x
                    + fmaxf(cg[mt][1] + b1.y, 0.f) * w2.y
                    + fmaxf(cg[mt][2] + b1.z, 0.f) * w2.z
                    + fmaxf(cg[mt][3] + b1.w, 0.f) * w2.w;
            s += __shfl_xor(s, 16, 64);
            s += __shfl_xor(s, 32, 64);
            epart[mt] += s;
        }
    }
    if (l4 == 0) {
        #pragma unroll
        for (int mt = 0; mt < 8; ++mt)
            evw[wv * 128 + mt * 16 + l15] = epart[mt];
    }
    __syncthreads();
    if (tid < 128)
        e[r0 + tid] = evw[tid] + evw[128 + tid] + evw[256 + tid] + evw[384 + tid];
}

// ---------------------------------------------------------------------------
// row-softmax helper: softmax over j (200 valid), bf16 store + pad zeroing
// ---------------------------------------------------------------------------
__device__ __forceinline__ void rowsm_store(
    float v0, float v1, float v2, float v3,
    bool act, int lane, int j4, short* __restrict__ dst)
{
    float mx = fmaxf(fmaxf(v0, v1), fmaxf(v2, v3));
    #pragma unroll
    for (int off = 32; off >= 1; off >>= 1) mx = fmaxf(mx, __shfl_xor(mx, off, 64));
    float p0 = act ? __expf(v0 - mx) : 0.f;
    float p1 = act ? __expf(v1 - mx) : 0.f;
    float p2 = act ? __expf(v2 - mx) : 0.f;
    float p3 = act ? __expf(v3 - mx) : 0.f;
    float s = p0 + p1 + p2 + p3;
    #pragma unroll
    for (int off = 32; off >= 1; off >>= 1) s += __shfl_xor(s, off, 64);
    float inv = 1.f / s;
    if (act) {
        uint2 st;
        st.x = cvtpk(p0 * inv, p1 * inv);
        st.y = cvtpk(p2 * inv, p3 * inv);
        *(uint2*)(dst + j4) = st;
    } else if (lane < 56) {
        uint2 z; z.x = 0u; z.y = 0u;
        *(uint2*)(dst + 200 + (lane - 50) * 4) = z;   // zero pad cols 200..223
    }
}

// ---------------------------------------------------------------------------
// Kernel C (combine): channel softmax + gated sum + mask + row softmax -> p
// grid (25, nbh), 256 threads. Wave wv owns rows wv and wv+4.
// ---------------------------------------------------------------------------
__global__ __launch_bounds__(256) void combine_kernel(
    const short* __restrict__ S,
    const float* __restrict__ e,         // chunk-offset pointer
    const float* __restrict__ mask,
    short* __restrict__ p9,              // [NBH][208][224] bf16
    short* __restrict__ p4,
    int bh0)
{
    const int rt  = blockIdx.x;
    const int bhl = blockIdx.y;
    const int bh  = bh0 + bhl;
    const int b   = bh >> 2;
    const int r0  = rt * 8;
    const int tid = threadIdx.x;
    const int lane = tid & 63, wv = tid >> 6;

    __shared__ float el[13][8];
    if (tid < 104) {
        int c = tid >> 3, r = tid & 7;
        el[c][r] = e[(size_t)(bhl * 13 + c) * Sc + r0 + r];
    }
    __syncthreads();

    const bool act = lane < 50;
    const int j4 = lane * 4;
    const short* Sb = S + (size_t)bhl * 13 * Sc * 224;

    #pragma unroll
    for (int rr = 0; rr < 2; ++rr) {
        const int row = wv + rr * 4;              // 0..7

        float wch9[9], wch4[4];
        {
            float mx = -1e30f;
            #pragma unroll
            for (int c = 0; c < 9; ++c) mx = fmaxf(mx, el[c][row]);
            float su = 0.f;
            #pragma unroll
            for (int c = 0; c < 9; ++c) { wch9[c] = __expf(el[c][row] - mx); su += wch9[c]; }
            float iv = 1.f / su;
            #pragma unroll
            for (int c = 0; c < 9; ++c) wch9[c] *= iv;
        }
        {
            float mx = -1e30f;
            #pragma unroll
            for (int c = 0; c < 4; ++c) mx = fmaxf(mx, el[9 + c][row]);
            float su = 0.f;
            #pragma unroll
            for (int c = 0; c < 4; ++c) { wch4[c] = __expf(el[9 + c][row] - mx); su += wch4[c]; }
            float iv = 1.f / su;
            #pragma unroll
            for (int c = 0; c < 4; ++c) wch4[c] *= iv;
        }

        float v9[4], v4v[4];
        if (act) {
            float g9[4] = {0.f, 0.f, 0.f, 0.f};
            float g4[4] = {0.f, 0.f, 0.f, 0.f};
            #pragma unroll
            for (int c = 0; c < 9; ++c) {
                bf16x4 sv = *(const bf16x4*)(Sb + (size_t)(c * Sc + r0 + row) * 224 + j4);
                float wc = wch9[c];
                #pragma unroll
                for (int i = 0; i < 4; ++i) g9[i] += wc * bf2f(sv[i]);
            }
            #pragma unroll
            for (int c = 0; c < 4; ++c) {
                bf16x4 sv = *(const bf16x4*)(Sb + (size_t)((9 + c) * Sc + r0 + row) * 224 + j4);
                float wc = wch4[c];
                #pragma unroll
                for (int i = 0; i < 4; ++i) g4[i] += wc * bf2f(sv[i]);
            }
            float4 mr = *(const float4*)(mask + ((size_t)b * Sc + r0 + row) * Sc + j4);
            v9[0] = g9[0] * SCALE + mr.x; v9[1] = g9[1] * SCALE + mr.y;
            v9[2] = g9[2] * SCALE + mr.z; v9[3] = g9[3] * SCALE + mr.w;
            v4v[0] = g4[0] * SCALE + mr.x; v4v[1] = g4[1] * SCALE + mr.y;
            v4v[2] = g4[2] * SCALE + mr.z; v4v[3] = g4[3] * SCALE + mr.w;
        } else {
            #pragma unroll
            for (int i = 0; i < 4; ++i) { v9[i] = -1e30f; v4v[i] = -1e30f; }
        }

        rowsm_store(v9[0], v9[1], v9[2], v9[3], act, lane, j4,
                    p9 + (size_t)(bh * 208 + r0 + row) * 224);
        rowsm_store(v4v[0], v4v[1], v4v[2], v4v[3], act, lane, j4,
                    p4 + (size_t)(bh * 208 + r0 + row) * 224);
    }
}

// ---------------------------------------------------------------------------
// Kernel D (PV): ctx[m][d] = sum_j p[m][j] * Vt[d][j]  per (bh, tensor)
// grid 512, 256 threads. Vt panel in LDS.
// ---------------------------------------------------------------------------
__global__ __launch_bounds__(256) void pv_kernel(
    const short* __restrict__ p9, const short* __restrict__ p4,
    const short* __restrict__ vt,
    short* __restrict__ ctxb, short* __restrict__ ctxcb)
{
    const int bid = blockIdx.x;
    const int t  = bid >> 8;
    const int bh = bid & 255;
    const int b = bh >> 2, h = bh & 3;
    const int tid = threadIdx.x;
    const int lane = tid & 63, wv = tid >> 6;
    const int l15 = lane & 15, l4 = lane >> 4;

    const short* pb = (t ? p4 : p9) + (size_t)bh * 208 * 224;
    const short* vb = vt + ((size_t)t * NBH + bh) * 64 * 224;
    short* cout = t ? ctxcb : ctxb;

    __shared__ __align__(16) short Vl[64 * 232];
    for (int i = tid; i < 64 * 28; i += 256) {
        int r = i / 28, c8 = i % 28;
        *(bf16x8*)(Vl + r * 232 + c8 * 8) = *(const bf16x8*)(vb + (size_t)r * 224 + c8 * 8);
    }
    __syncthreads();

    for (int mt = wv; mt < 13; mt += 4) {
        f32x4 acc[4];
        #pragma unroll
        for (int dt = 0; dt < 4; ++dt) acc[dt] = (f32x4){};
        #pragma unroll
        for (int ks = 0; ks < 7; ++ks) {
            bf16x8 af = *(const bf16x8*)(pb + (size_t)(mt * 16 + l15) * 224 + ks * 32 + l4 * 8);
            #pragma unroll
            for (int dt = 0; dt < 4; ++dt) {
                bf16x8 bb = *(const bf16x8*)(Vl + (dt * 16 + l15) * 232 + ks * 32 + l4 * 8);
                acc[dt] = mfma16(af, bb, acc[dt]);
            }
        }
        int mrow = mt * 16 + l4 * 4;
        if (mrow < Sc) {
            #pragma unroll
            for (int dt = 0; dt < 4; ++dt) {
                #pragma unroll
                for (int i = 0; i < 4; ++i)
                    cout[(size_t)(b * Sc + mrow + i) * Dc + h * HDc + dt * 16 + l15] =
                        f2bf(acc[dt][i]);
            }
        }
    }
}

// ---------------------------------------------------------------------------
// Kernel 3 (MFMA, merged both outputs):
// out = LayerNorm( ctx(bf16) @ WdT + bias + resid ) * g + b
// ---------------------------------------------------------------------------
__global__ __launch_bounds__(256, 3) void out_ln2(
    const short* __restrict__ ctxb, const short* __restrict__ ctxcb,
    const short* __restrict__ WT15, const short* __restrict__ WT16,
    const float* __restrict__ bd,   const float* __restrict__ bda,
    const float* __restrict__ X,    const float* __restrict__ HA,
    const float* __restrict__ g0,   const float* __restrict__ be0,
    const float* __restrict__ g1,   const float* __restrict__ be1,
    float* __restrict__ out0,       float* __restrict__ out1)
{
    const int bidx = blockIdx.x;
    const bool sec = bidx >= 400;
    const short* Ab    = sec ? ctxcb : ctxb;
    const short* WTp   = sec ? WT16 : WT15;
    const float* bias  = sec ? bda : bd;
    const float* resid = sec ? HA : X;
    const float* gamma = sec ? g1 : g0;
    const float* beta  = sec ? be1 : be0;
    float* out = sec ? out1 : out0;
    const int m0 = (sec ? bidx - 400 : bidx) * 32;

    __shared__ __align__(16) short As[32 * 264];
    __shared__ float ylds[32][257];
    const int tid = threadIdx.x;
    const int lane = tid & 63, wv = tid >> 6;
    const int l15 = lane & 15, l4 = lane >> 4;

    for (int t = tid; t < 32 * 32; t += 256) {
        int r = t >> 5, c8 = t & 31;
        *(bf16x8*)(As + r * 264 + c8 * 8) = *(const bf16x8*)(Ab + (size_t)(m0 + r) * Dc + c8 * 8);
    }
    __syncthreads();

    const int nb = wv * 64;
    f32x4 acc[2][4];
    #pragma unroll
    for (int mi = 0; mi < 2; ++mi)
        #pragma unroll
        for (int ni = 0; ni < 4; ++ni) acc[mi][ni] = (f32x4){};

    #pragma unroll
    for (int ks = 0; ks < 8; ++ks) {
        bf16x8 bfr[4];
        #pragma unroll
        for (int ni = 0; ni < 4; ++ni)
            bfr[ni] = *(const bf16x8*)(WTp + (size_t)(nb + ni * 16 + l15) * Dc + ks * 32 + l4 * 8);
        #pragma unroll
        for (int mi = 0; mi < 2; ++mi) {
            bf16x8 a = *(const bf16x8*)(As + (mi * 16 + l15) * 264 + ks * 32 + l4 * 8);
            #pragma unroll
            for (int ni = 0; ni < 4; ++ni)
                acc[mi][ni] = mfma16(a, bfr[ni], acc[mi][ni]);
        }
    }

    #pragma unroll
    for (int mi = 0; mi < 2; ++mi) {
        #pragma unroll
        for (int ni = 0; ni < 4; ++ni) {
            int n = nb + ni * 16 + l15;
            float bv = bias[n];
            #pragma unroll
            for (int i = 0; i < 4; ++i) {
                int row = mi * 16 + l4 * 4 + i;
                ylds[row][n] = acc[mi][ni][i] + bv + resid[(size_t)(m0 + row) * Dc + n];
            }
        }
    }
    __syncthreads();

    for (int r = wv * 8; r < wv * 8 + 8; ++r) {
        float v4[4];
        float s = 0.f, s2 = 0.f;
        #pragma unroll
        for (int t4 = 0; t4 < 4; ++t4) {
            float v = ylds[r][t4 * 64 + lane];
            v4[t4] = v;
            s += v; s2 += v * v;
        }
        #pragma unroll
        for (int off = 32; off >= 1; off >>= 1) {
            s  += __shfl_xor(s, off, 64);
            s2 += __shfl_xor(s2, off, 64);
        }
        float m   = s * (1.f / 256.f);
        float var = s2 * (1.f / 256.f) - m * m;
        float rstd = rsqrtf(var + 1e-12f);
        #pragma unroll
        for (int t4 = 0; t4 < 4; ++t4) {
            int ccol = t4 * 64 + lane;
            out[(size_t)(m0 + r) * Dc + ccol] = (v4[t4] - m) * rstd * gamma[ccol] + beta[ccol];
        }
    }
}

// ---------------------------------------------------------------------------
// Launcher
// ---------------------------------------------------------------------------
extern "C" void kernel_launch(void* const* d_in, const int* in_sizes, int n_in,
                              void* d_out, int out_size, void* d_ws, size_t ws_size,
                              hipStream_t stream) {
    const float* X    = (const float*)d_in[0];
    const float* AT   = (const float*)d_in[1];
    const float* P    = (const float*)d_in[2];
    const float* HA   = (const float*)d_in[3];
    const float* mask = (const float*)d_in[4];
    const float* fw   = (const float*)d_in[5];
    const float* fwc  = (const float*)d_in[6];

    const float* Wq   = (const float*)d_in[7];
    const float* bq   = (const float*)d_in[8];
    const float* Wk   = (const float*)d_in[9];
    const float* bk   = (const float*)d_in[10];
    const float* Wv   = (const float*)d_in[11];
    const float* bv   = (const float*)d_in[12];
    const float* Wqp  = (const float*)d_in[13];
    const float* bqp  = (const float*)d_in[14];
    const float* Wkp  = (const float*)d_in[15];
    const float* bkp  = (const float*)d_in[16];
    const float* Waq  = (const float*)d_in[17];
    const float* baq  = (const float*)d_in[18];
    const float* Wak  = (const float*)d_in[19];
    const float* bak  = (const float*)d_in[20];
    const float* Wav  = (const float*)d_in[21];
    const float* bav  = (const float*)d_in[22];
    const float* Wqic = (const float*)d_in[23];
    const float* bqic = (const float*)d_in[24];
    const float* Wqci = (const float*)d_in[25];
    const float* bqci = (const float*)d_in[26];
    const float* Wqpc = (const float*)d_in[27];
    const float* bqpc = (const float*)d_in[28];
    const float* Wqcp = (const float*)d_in[29];
    const float* bqcp = (const float*)d_in[30];
    const float* Wf1  = (const float*)d_in[31];
    const float* bf1  = (const float*)d_in[32];
    const float* Wf2  = (const float*)d_in[33];
    const float* bf2  = (const float*)d_in[34];
    const float* Wd   = (const float*)d_in[35];
    const float* bd   = (const float*)d_in[36];
    const float* ln_g = (const float*)d_in[37];
    const float* ln_b = (const float*)d_in[38];
    const float* Wda  = (const float*)d_in[39];
    const float* bda  = (const float*)d_in[40];
    const float* lna_g= (const float*)d_in[41];
    const float* lna_b= (const float*)d_in[42];

    char* w = (char*)d_ws;
    short* proj_bf = (short*)w;  w += (size_t)NPROJ * NPc * Dc * sizeof(short);
    short* WTall   = (short*)w;  w += (size_t)NWT * Dc * Dc * sizeof(short);
    short* WTf1    = (short*)w;  w += (size_t)224 * 224 * sizeof(short);
    short* inb     = (short*)w;  w += (size_t)4 * NPc * Dc * sizeof(short);
    short* vt      = (short*)w;  w += (size_t)2 * NBH * 64 * 224 * sizeof(short);
    short* ctxb    = (short*)w;  w += (size_t)NPc * Dc * sizeof(short);
    short* ctxcb   = (short*)w;  w += (size_t)NPc * Dc * sizeof(short);
    float* ebuf    = (float*)w;  w += (size_t)NBH * 13 * Sc * sizeof(float);
    short* p9      = (short*)w;  w += (size_t)NBH * 208 * 224 * sizeof(short);
    short* p4      = (short*)w;  w += (size_t)NBH * 208 * 224 * sizeof(short);
    size_t base_bytes = (size_t)(w - (char*)d_ws);
    short* Sbuf    = (short*)w;

    // choose bh-chunking so S fits in remaining workspace (deterministic)
    const size_t S_full = (size_t)NBH * 13 * Sc * 224 * sizeof(short);
    int nch = 1;
    while (nch < 16 && base_bytes + S_full / nch > ws_size) nch *= 2;
    const int nbh = NBH / nch;

    const int aid[NPROJ] = {0,0,0,2,2,1,1,3,3,3,0,1,1,3,2};
    const float* Wmat[NWT] = {Wq, Wk, Wv, Wqp, Wkp, Waq, Wak, Waq, Wak, Wav,
                              Wqic, Wqci, Wqcp, Wqcp, Wqpc, Wd, Wda};
    const float* bmat[NPROJ] = {bq, bk, bv, bqp, bkp, baq, bak, baq, bak, bav,
                                bqic, bqci, bqcp, bqcp, bqpc};

    ProjArgsM pm;
    WList wl;
    for (int i = 0; i < NPROJ; i++) {
        pm.A[i]    = inb + (size_t)aid[i] * NPc * Dc;
        pm.bias[i] = bmat[i];
    }
    for (int i = 0; i < NWT; i++) wl.w[i] = Wmat[i];

    // 0. prep (casts + weight transposes)
    prep_kernel<<<13268, 256, 0, stream>>>(X, AT, P, HA, inb, wl, WTall, Wf1, WTf1);

    // 1. projections (MFMA, bf16 in/out)
    proj_mfma<<<dim3(NPc / 64, NPROJ), 256, 0, stream>>>(pm, WTall, proj_bf);

    // 1b. V transpose (iv, hav) -> vt bf16
    vt_kernel<<<512, 256, 0, stream>>>(proj_bf, vt);

    // 2. scores -> gate -> combine, per bh-chunk
    for (int ch = 0; ch < nch; ++ch) {
        int bh0 = ch * nbh;
        scores_kernel<<<dim3(13, nbh), 256, 0, stream>>>(proj_bf, fw, fwc, Sbuf, bh0);
        gate_kernel<<<(nbh * 13 * Sc) / 128, 256, 0, stream>>>(
            Sbuf, WTf1, bf1, Wf2, ebuf + (size_t)bh0 * 13 * Sc);
        combine_kernel<<<dim3(25, nbh), 256, 0, stream>>>(
            Sbuf, ebuf + (size_t)bh0 * 13 * Sc, mask, p9, p4, bh0);
    }

    // 3. PV (both tensors)
    pv_kernel<<<512, 256, 0, stream>>>(p9, p4, vt, ctxb, ctxcb);

    // 4. output projections + residual + LayerNorm (MFMA)
    out_ln2<<<800, 256, 0, stream>>>(ctxb, ctxcb,
                                     WTall + (size_t)15 * Dc * Dc,
                                     WTall + (size_t)16 * Dc * Dc,
                                     bd, bda, X, HA,
                                     ln_g, ln_b, lna_g, lna_b,
                                     (float*)d_out, (float*)d_out + (size_t)NPc * Dc);
}

// Round 16
// 459.434 us; speedup vs baseline: 1.3276x; 1.3276x over previous
//
#include <hip/hip_runtime.h>
#include <cstddef>

typedef __attribute__((ext_vector_type(8))) short bf16x8;
typedef __attribute__((ext_vector_type(4))) short bf16x4;
typedef __attribute__((ext_vector_type(4))) float f32x4;

constexpr int Bc = 64;
constexpr int Sc = 200;
constexpr int Hc = 4;
constexpr int Dc = 256;
constexpr int HDc = 64;
constexpr int NPc = Bc * Sc;          // 12800 rows
constexpr int NPROJ = 15;
constexpr int NWT   = 17;             // 15 proj weights + Wd + Wda
constexpr int SLD   = 232;            // S row stride (shorts); cols 224-231 hold evw
constexpr float SCALE = 0.125f;       // 1/sqrt(64)

// proj indices
// 0 iq, 1 ik, 2 iv, 3 pq, 4 pk, 5 aq, 6 ak, 7 haq, 8 hak, 9 hav,
// 10 iqc, 11 ciq, 12 cqp, 13 cqp_a, 14 pqc

__constant__ int c_KP9[3]  = {1,6,4};                   // K proj per group
__constant__ int c_QP9[9]  = {0,11,3, 10,5,14, 0,12,3}; // Q proj per (g,k) slot
__constant__ int c_CG9[9]  = {0,3,6, 1,4,7, 2,5,8};     // slot -> channel
__constant__ int c_M2S9[9] = {0,24,48,8,32,56,16,40,64};// channel -> S row base
__constant__ int c_KP4[2]  = {8,4};
__constant__ int c_QP4[4]  = {7,14, 13,3};
__constant__ int c_CG4[4]  = {0,2, 1,3};
__constant__ int c_M2S4[4] = {0,16,8,24};

__device__ __forceinline__ short f2bf(float x) {
    union { float f; unsigned u; } v; v.f = x;
    unsigned r = v.u + 0x7FFFu + ((v.u >> 16) & 1u);
    return (short)(r >> 16);
}
__device__ __forceinline__ float bf2f(short x) {
    union { unsigned u; float f; } v; v.u = ((unsigned)(unsigned short)x) << 16;
    return v.f;
}
__device__ __forceinline__ unsigned cvtpk(float lo, float hi) {
    unsigned r;
    asm("v_cvt_pk_bf16_f32 %0, %1, %2" : "=v"(r) : "v"(lo), "v"(hi));
    return r;
}
__device__ __forceinline__ f32x4 mfma16(bf16x8 a, bf16x8 b, f32x4 c) {
    return __builtin_amdgcn_mfma_f32_16x16x32_bf16(a, b, c, 0, 0, 0);
}

struct ProjArgsM {
    const short* A[NPROJ];      // bf16 input per projection
    const float* bias[NPROJ];
};
struct WList { const float* w[NWT]; };

// ---------------------------------------------------------------------------
// prep: cast_in (blocks 0..12799) + cast_wt (12800..13071) + wf1t (13072..13267)
// ---------------------------------------------------------------------------
__global__ __launch_bounds__(256) void prep_kernel(
    const float* __restrict__ X, const float* __restrict__ AT,
    const float* __restrict__ P, const float* __restrict__ HA,
    short* __restrict__ inb,
    WList wl, short* __restrict__ WTall,
    const float* __restrict__ Wf1, short* __restrict__ WTf1)
{
    __shared__ float tbuf[64][65];
    const int bid = blockIdx.x;
    const int tid = threadIdx.x;

    if (bid < 12800) {
        int ten = bid / 3200, blk = bid - ten * 3200;
        const float* srcs[4] = {X, AT, P, HA};
        const float* src = srcs[ten];
        short* d = inb + (size_t)ten * NPc * Dc;
        int t = blk * 256 + tid;
        float4 v = ((const float4*)src)[t];
        uint2 st;
        st.x = cvtpk(v.x, v.y);
        st.y = cvtpk(v.z, v.w);
        *(uint2*)(d + (size_t)t * 4) = st;
    } else if (bid < 13072) {
        int q = bid - 12800;
        int p = q >> 4, tile = q & 15;
        int k0 = (tile >> 2) * 64, n0 = (tile & 3) * 64;
        const float* W = wl.w[p];
        short* d = WTall + (size_t)p * Dc * Dc;
        for (int i = tid; i < 64 * 64; i += 256) {
            int k = i >> 6, n = i & 63;
            tbuf[k][n] = W[(size_t)(k0 + k) * Dc + n0 + n];
        }
        __syncthreads();
        for (int i = tid; i < 64 * 64; i += 256) {
            int n = i >> 6, k = i & 63;
            d[(size_t)(n0 + n) * Dc + k0 + k] = f2bf(tbuf[k][n]);
        }
    } else {
        int t = (bid - 13072) * 256 + tid;
        if (t < 224 * 224) {
            int j = t / 224, i = t % 224;
            WTf1[t] = (i < Sc && j < Sc) ? f2bf(Wf1[(size_t)i * Sc + j]) : (short)0;
        }
    }
}

// ---------------------------------------------------------------------------
// V transpose: proj_bf[p={2,9}] head strips -> vt[t][(b*4+h)][64][224] bf16
// ---------------------------------------------------------------------------
__global__ __launch_bounds__(256) void vt_kernel(const short* __restrict__ proj_bf,
                                                 short* __restrict__ vt) {
    const int bid = blockIdx.x;
    const int t  = bid >> 8;
    const int bh = bid & 255;
    const int b = bh >> 2, h = bh & 3;
    const int p = t ? 9 : 2;
    const short* src = proj_bf + ((size_t)p * NPc + (size_t)b * Sc) * Dc + h * HDc;
    short* dst = vt + ((size_t)t * 256 + bh) * 64 * 224;
    __shared__ short tile[200][72];
    const int tid = threadIdx.x;
    for (int idx = tid; idx < 200 * 8; idx += 256) {
        int j = idx >> 3, c8 = idx & 7;
        *(bf16x8*)(&tile[j][c8 * 8]) = *(const bf16x8*)(src + (size_t)j * Dc + c8 * 8);
    }
    __syncthreads();
    for (int idx = tid; idx < 64 * 28; idx += 256) {
        int d = idx / 28, c8 = idx % 28;
        bf16x8 o;
        #pragma unroll
        for (int i = 0; i < 8; ++i) {
            int j = c8 * 8 + i;
            o[i] = (j < 200) ? tile[j][d] : (short)0;
        }
        *(bf16x8*)(dst + (size_t)d * 224 + c8 * 8) = o;
    }
}

// ---------------------------------------------------------------------------
// Kernel 1 (MFMA): all 15 projections. C[64 x 256] tile per block. bf16 out.
// Epilogue: C staged in LDS (stride 280), then full-line coalesced stores
// (old scalar-store epilogue wrote 32B segments -> L2 partial-line RMW,
//  proj capped at 1.9 TB/s per R15 counters).
// ---------------------------------------------------------------------------
__global__ __launch_bounds__(256, 4) void proj_mfma(
    ProjArgsM args, const short* __restrict__ WTall, short* __restrict__ proj_bf)
{
    const int p  = blockIdx.y;
    const int m0 = blockIdx.x * 64;
    const short* __restrict__ A   = args.A[p];
    const short* __restrict__ WTp = WTall + (size_t)p * Dc * Dc;
    const float* __restrict__ bias = args.bias[p];
    short* __restrict__ ob = proj_bf + (size_t)p * NPc * Dc;

    __shared__ __align__(16) short As[64 * 280];
    const int tid = threadIdx.x;
    const int lane = tid & 63, w = tid >> 6;
    const int l15 = lane & 15, l4 = lane >> 4;

    for (int t = tid; t < 64 * 32; t += 256) {
        int r = t >> 5, c8 = t & 31;
        *(bf16x8*)(As + r * 280 + c8 * 8) = *(const bf16x8*)(A + (size_t)(m0 + r) * Dc + c8 * 8);
    }
    __syncthreads();

    f32x4 acc[4][4];
    #pragma unroll
    for (int mi = 0; mi < 4; ++mi)
        #pragma unroll
        for (int ni = 0; ni < 4; ++ni) acc[mi][ni] = (f32x4){};

    const int nb = w * 64;
    #pragma unroll
    for (int ks = 0; ks < 8; ++ks) {
        bf16x8 bfr[4];
        #pragma unroll
        for (int ni = 0; ni < 4; ++ni)
            bfr[ni] = *(const bf16x8*)(WTp + (size_t)(nb + ni * 16 + l15) * Dc + ks * 32 + l4 * 8);
        #pragma unroll
        for (int mi = 0; mi < 4; ++mi) {
            bf16x8 a = *(const bf16x8*)(As + (mi * 16 + l15) * 280 + ks * 32 + l4 * 8);
            #pragma unroll
            for (int ni = 0; ni < 4; ++ni)
                acc[mi][ni] = mfma16(a, bfr[ni], acc[mi][ni]);
        }
    }

    float bv[4];
    #pragma unroll
    for (int ni = 0; ni < 4; ++ni) bv[ni] = bias[nb + ni * 16 + l15];

    __syncthreads();   // all As reads complete before overwrite

    // stage C (bf16) into As: [64 rows][stride 280], cols 0..255
    #pragma unroll
    for (int mi = 0; mi < 4; ++mi) {
        #pragma unroll
        for (int ni = 0; ni < 4; ++ni) {
            int n = nb + ni * 16 + l15;
            int mloc = mi * 16 + l4 * 4;
            #pragma unroll
            for (int i = 0; i < 4; ++i)
                As[(mloc + i) * 280 + n] = f2bf(acc[mi][ni][i] + bv[ni]);
        }
    }
    __syncthreads();

    // coalesced stores: per pass, wave writes 2 rows x 1KB contiguous
    #pragma unroll
    for (int pp = 0; pp < 8; ++pp) {
        int r  = pp * 8 + (tid >> 5);
        int c0 = (tid & 31) * 8;
        *(bf16x8*)(ob + (size_t)(m0 + r) * Dc + c0) = *(const bf16x8*)(As + r * 280 + c0);
    }
}

// ---------------------------------------------------------------------------
// fused body (v9/v12 structure — proven 374 us, VGPR 84, no spills).
// R5/R8/R11/R12: any added live state spills; R15: S-materialization loses.
// ---------------------------------------------------------------------------
template <int CH, int NG, int CPG, int QT, int MT2>
__device__ void fused_body(
    int bid,
    const short* __restrict__ proj_bf,
    const short* __restrict__ vtb,       // [256][64][224] bf16 (per (b,h))
    const float* __restrict__ fw,
    const float* __restrict__ mask,
    const short* __restrict__ WT,
    const float* __restrict__ bf1,
    const float* __restrict__ Wf2,
    short* __restrict__ ctx_out,         // bf16 [NPc][256]
    const int* KP, const int* QP, const int* CG, const int* M2S,
    short* Sl, float* fwl, float* bf1l, float* wf2l)
{
    constexpr int GR    = CPG * 8;       // valid S rows per group
    constexpr int VROWS = NG * GR;       // total valid S rows
    constexpr int SROWS = MT2 * 16;
    constexpr int NW    = 4;

    const int tid = threadIdx.x;
    const int rt  = bid % 25;
    const int h   = (bid / 25) & 3;
    const int b   = bid / 100;
    const int r0  = rt * 8;
    const int lane = tid & 63, wv = tid >> 6;   // wv 0..3
    const int l15 = lane & 15, l4 = lane >> 4;
    const int brow0 = b * Sc + r0;

    // ---- phase 0: zero pad regions of Sl (cols 0..223 only); stage bf1/Wf2; fw
    {
        bf16x8 z = {};
        if constexpr (SROWS > VROWS) {
            for (int t = tid; t < (SROWS - VROWS) * 28; t += 256) {
                int r = VROWS + t / 28, c8 = t % 28;
                *(bf16x8*)(Sl + r * SLD + c8 * 8) = z;
            }
        }
        for (int t = tid; t < VROWS * 3; t += 256) {
            int r = t / 3, c8 = t % 3;
            *(bf16x8*)(Sl + r * SLD + 200 + c8 * 8) = z;
        }
    }
    if (tid < 224) {
        bf1l[tid] = (tid < Sc) ? bf1[tid] : 0.f;
        wf2l[tid] = (tid < Sc) ? Wf2[tid] : 0.f;
    }
    if (tid < CH) fwl[tid] = fw[tid];

    // ---- preload Q A-fragments from global (registers)
    bf16x8 af[NG][QT][2];
    #pragma unroll
    for (int g = 0; g < NG; ++g) {
        #pragma unroll
        for (int t = 0; t < QT; ++t) {
            int sr = t * 16 + l15;
            int kk = (sr < GR) ? (sr >> 3) : 0;
            int rr = (sr < GR) ? (sr & 7) : 0;
            const short* qp = proj_bf + ((size_t)QP[g * CPG + kk] * NPc + brow0 + rr) * Dc + h * HDc;
            #pragma unroll
            for (int ks = 0; ks < 2; ++ks)
                af[g][t][ks] = *(const bf16x8*)(qp + ks * 32 + l4 * 8);
        }
    }
    __syncthreads();

    // ---- scores (pipelined over nt): S[m][j] = fw[c] * (q_m . k_j)
    {
        const short* Kb[NG];
        #pragma unroll
        for (int g = 0; g < NG; ++g)
            Kb[g] = proj_bf + ((size_t)KP[g] * NPc + (size_t)b * Sc) * Dc + h * HDc;

        float fwv[NG][QT];
        #pragma unroll
        for (int g = 0; g < NG; ++g)
            #pragma unroll
            for (int t = 0; t < QT; ++t) {
                int k = t * 2 + (l4 >> 1);
                fwv[g][t] = (k < CPG) ? fwl[CG[g * CPG + k]] : 0.f;
            }

        bf16x8 cur[NG][2];
        int nt = wv;
        {
            int j = nt * 16 + l15;
            #pragma unroll
            for (int g = 0; g < NG; ++g) {
                cur[g][0] = *(const bf16x8*)(Kb[g] + (size_t)j * Dc + l4 * 8);
                cur[g][1] = *(const bf16x8*)(Kb[g] + (size_t)j * Dc + 32 + l4 * 8);
            }
        }
        while (nt < 13) {
            const int ntn = nt + NW;
            bf16x8 nxt[NG][2];
            if (ntn < 13) {
                int j2 = ntn * 16 + l15;
                #pragma unroll
                for (int g = 0; g < NG; ++g) {
                    nxt[g][0] = *(const bf16x8*)(Kb[g] + (size_t)j2 * Dc + l4 * 8);
                    nxt[g][1] = *(const bf16x8*)(Kb[g] + (size_t)j2 * Dc + 32 + l4 * 8);
                }
            }
            const int j = nt * 16 + l15;
            const bool jv = (j < Sc);
            #pragma unroll
            for (int g = 0; g < NG; ++g) {
                #pragma unroll
                for (int t = 0; t < QT; ++t) {
                    f32x4 c = {};
                    c = mfma16(af[g][t][0], cur[g][0], c);
                    c = mfma16(af[g][t][1], cur[g][1], c);
                    int k = t * 2 + (l4 >> 1);
                    if (jv && k < CPG) {
                        int srb = g * GR + t * 16 + l4 * 4;
                        float f = fwv[g][t];
                        unsigned p01 = cvtpk(c[0] * f, c[1] * f);
                        unsigned p23 = cvtpk(c[2] * f, c[3] * f);
                        Sl[(srb + 0) * SLD + j] = (short)p01;
                        Sl[(srb + 1) * SLD + j] = (short)(p01 >> 16);
                        Sl[(srb + 2) * SLD + j] = (short)p23;
                        Sl[(srb + 3) * SLD + j] = (short)(p23 >> 16);
                    }
                }
            }
            #pragma unroll
            for (int g = 0; g < NG; ++g) { cur[g][0] = nxt[g][0]; cur[g][1] = nxt[g][1]; }
            nt = ntn;
        }
    }
    __syncthreads();

    // ---- gate: Y[j][m] via MFMA(A=WT rows j, B=Sl rows m); e[m] partials ->
    //      embedded evw at Sl cols 224..231 (float, slot per wave)
    {
        float epart[MT2];
        #pragma unroll
        for (int mt = 0; mt < MT2; ++mt) epart[mt] = 0.f;

        for (int nt = wv; nt < 13; nt += NW) {
            const int jr = nt * 16 + l15;
            bf16x8 wfrag[7];
            #pragma unroll
            for (int ks = 0; ks < 7; ++ks)
                wfrag[ks] = *(const bf16x8*)(WT + (size_t)jr * 224 + ks * 32 + l4 * 8);
            f32x4 cg[MT2];
            #pragma unroll
            for (int mt = 0; mt < MT2; ++mt) cg[mt] = (f32x4){};
            #pragma unroll
            for (int ks = 0; ks < 7; ++ks) {
                #pragma unroll
                for (int mt = 0; mt < MT2; ++mt) {
                    bf16x8 bb = *(const bf16x8*)(Sl + (mt * 16 + l15) * SLD + ks * 32 + l4 * 8);
                    cg[mt] = mfma16(wfrag[ks], bb, cg[mt]);
                }
            }
            float4 b1 = *(const float4*)(bf1l + nt * 16 + l4 * 4);
            float4 w2 = *(const float4*)(wf2l + nt * 16 + l4 * 4);
            #pragma unroll
            for (int mt = 0; mt < MT2; ++mt) {
                float s = fmaxf(cg[mt][0] + b1.x, 0.f) * w2.x
                        + fmaxf(cg[mt][1] + b1.y, 0.f) * w2.y
                        + fmaxf(cg[mt][2] + b1.z, 0.f) * w2.z
                        + fmaxf(cg[mt][3] + b1.w, 0.f) * w2.w;
                s += __shfl_xor(s, 16, 64);
                s += __shfl_xor(s, 32, 64);
                epart[mt] += s;
            }
        }
        if (l4 == 0) {
            #pragma unroll
            for (int mt = 0; mt < MT2; ++mt)
                *(float*)(Sl + (size_t)(mt * 16 + l15) * SLD + 224 + wv * 2) = epart[mt];
        }
    }
    __syncthreads();

    // ================= wave-local tail: rows ra=wv, rb=wv+4 =================
    const int ra = wv, rb = wv + 4;

    // ---- channel softmax (redundant per wave, register result)
    float wchA[CH], wchB[CH];
    {
        float eA[CH], eB[CH];
        float mxA = -1e30f, mxB = -1e30f;
        #pragma unroll
        for (int c = 0; c < CH; ++c) {
            int m = M2S[c];
            float sA = 0.f, sB = 0.f;
            #pragma unroll
            for (int w = 0; w < NW; ++w) {
                sA += *(const float*)(Sl + (size_t)(m + ra) * SLD + 224 + w * 2);
                sB += *(const float*)(Sl + (size_t)(m + rb) * SLD + 224 + w * 2);
            }
            eA[c] = sA; eB[c] = sB;
            mxA = fmaxf(mxA, sA); mxB = fmaxf(mxB, sB);
        }
        float suA = 0.f, suB = 0.f;
        #pragma unroll
        for (int c = 0; c < CH; ++c) {
            eA[c] = __expf(eA[c] - mxA); suA += eA[c];
            eB[c] = __expf(eB[c] - mxB); suB += eB[c];
        }
        float ivA = 1.f / suA, ivB = 1.f / suB;
        #pragma unroll
        for (int c = 0; c < CH; ++c) { wchA[c] = eA[c] * ivA; wchB[c] = eB[c] * ivB; }
    }

    // ---- gated sum + scale + mask (j-contiguous: lane<50 owns j4..j4+3)
    const bool act = lane < 50;
    const int j4 = lane * 4;
    float vA[4], vB[4];
    if (act) {
        const float* mbase = mask + ((size_t)b * Sc + r0) * Sc;
        float aA[4] = {0.f, 0.f, 0.f, 0.f};
        float aB[4] = {0.f, 0.f, 0.f, 0.f};
        #pragma unroll
        for (int c = 0; c < CH; ++c) {
            bf16x4 sA = *(const bf16x4*)(Sl + (size_t)(M2S[c] + ra) * SLD + j4);
            bf16x4 sB = *(const bf16x4*)(Sl + (size_t)(M2S[c] + rb) * SLD + j4);
            float wA = wchA[c], wB = wchB[c];
            #pragma unroll
            for (int i = 0; i < 4; ++i) {
                aA[i] += wA * bf2f(sA[i]);
                aB[i] += wB * bf2f(sB[i]);
            }
        }
        float4 mA = *(const float4*)(mbase + (size_t)ra * Sc + j4);
        float4 mB = *(const float4*)(mbase + (size_t)rb * Sc + j4);
        vA[0] = aA[0] * SCALE + mA.x; vA[1] = aA[1] * SCALE + mA.y;
        vA[2] = aA[2] * SCALE + mA.z; vA[3] = aA[3] * SCALE + mA.w;
        vB[0] = aB[0] * SCALE + mB.x; vB[1] = aB[1] * SCALE + mB.y;
        vB[2] = aB[2] * SCALE + mB.z; vB[3] = aB[3] * SCALE + mB.w;
    } else {
        #pragma unroll
        for (int i = 0; i < 4; ++i) { vA[i] = -1e30f; vB[i] = -1e30f; }
    }

    // ---- row softmax A (register-resident), p -> Sl row ra (bf16)
    {
        float mx = fmaxf(fmaxf(vA[0], vA[1]), fmaxf(vA[2], vA[3]));
        #pragma unroll
        for (int off = 32; off >= 1; off >>= 1) mx = fmaxf(mx, __shfl_xor(mx, off, 64));
        float p0 = act ? __expf(vA[0] - mx) : 0.f;
        float p1 = act ? __expf(vA[1] - mx) : 0.f;
        float p2 = act ? __expf(vA[2] - mx) : 0.f;
        float p3 = act ? __expf(vA[3] - mx) : 0.f;
        float s = p0 + p1 + p2 + p3;
        #pragma unroll
        for (int off = 32; off >= 1; off >>= 1) s += __shfl_xor(s, off, 64);
        float inv = 1.f / s;
        if (act) {
            uint2 st;
            st.x = cvtpk(p0 * inv, p1 * inv);
            st.y = cvtpk(p2 * inv, p3 * inv);
            *(uint2*)(Sl + (size_t)ra * SLD + j4) = st;
        }
    }
    // ---- row softmax B, p -> Sl row rb (bf16)
    {
        float mx = fmaxf(fmaxf(vB[0], vB[1]), fmaxf(vB[2], vB[3]));
        #pragma unroll
        for (int off = 32; off >= 1; off >>= 1) mx = fmaxf(mx, __shfl_xor(mx, off, 64));
        float p0 = act ? __expf(vB[0] - mx) : 0.f;
        float p1 = act ? __expf(vB[1] - mx) : 0.f;
        float p2 = act ? __expf(vB[2] - mx) : 0.f;
        float p3 = act ? __expf(vB[3] - mx) : 0.f;
        float s = p0 + p1 + p2 + p3;
        #pragma unroll
        for (int off = 32; off >= 1; off >>= 1) s += __shfl_xor(s, off, 64);
        float inv = 1.f / s;
        if (act) {
            uint2 st;
            st.x = cvtpk(p0 * inv, p1 * inv);
            st.y = cvtpk(p2 * inv, p3 * inv);
            *(uint2*)(Sl + (size_t)rb * SLD + j4) = st;
        }
    }
    __syncthreads();

    // ---- PV via MFMA: A = p tile (Sl rows 0..15; 8 valid), B = Vt rows
    {
        const short* vb = vtb + ((size_t)(b * Hc + h) * 64) * 224;
        const int nb = wv * 16;
        f32x4 c0 = {}, c1 = {};
        #pragma unroll
        for (int ks = 0; ks < 7; ks += 2) {
            bf16x8 aa = *(const bf16x8*)(Sl + l15 * SLD + ks * 32 + l4 * 8);
            bf16x8 bb = *(const bf16x8*)(vb + (size_t)(nb + l15) * 224 + ks * 32 + l4 * 8);
            c0 = mfma16(aa, bb, c0);
            if (ks + 1 < 7) {
                bf16x8 aa1 = *(const bf16x8*)(Sl + l15 * SLD + (ks + 1) * 32 + l4 * 8);
                bf16x8 bb1 = *(const bf16x8*)(vb + (size_t)(nb + l15) * 224 + (ks + 1) * 32 + l4 * 8);
                c1 = mfma16(aa1, bb1, c1);
            }
        }
        if (l4 < 2) {
            #pragma unroll
            for (int i = 0; i < 4; ++i) {
                int row = l4 * 4 + i;
                ctx_out[((size_t)(brow0 + row)) * Dc + h * HDc + nb + l15] =
                    f2bf(c0[i] + c1[i]);
            }
        }
    }
}

// ---------------------------------------------------------------------------
// Kernel 2: merged fused attention, 256 threads, XCD-balanced swizzle.
// ---------------------------------------------------------------------------
__global__ __launch_bounds__(256, 3) void fused12(
    const short* __restrict__ proj_bf,
    const short* __restrict__ vt,        // [2][256][64][224]
    const float* __restrict__ fw9,
    const float* __restrict__ fw4,
    const float* __restrict__ mask,
    const short* __restrict__ WT,
    const float* __restrict__ bf1,
    const float* __restrict__ Wf2,
    short* __restrict__ ctxb,
    short* __restrict__ ctxcb)
{
    __shared__ __align__(16) short Sl[80 * SLD];
    __shared__ float fwl[9];
    __shared__ float bf1l[224];
    __shared__ float wf2l[224];

    const int d    = blockIdx.x;          // 0..12799
    const int xcd  = d & 7;
    const int slot = d >> 3;              // 0..1599
    const int chunk = (slot / 25) * 8 + xcd;
    const int pos   = slot % 25;
    const int bid   = chunk * 25 + pos;

    if (bid < 6400) {
        fused_body<9, 3, 3, 2, 5>(bid, proj_bf, vt, fw9, mask, WT, bf1, Wf2, ctxb,
                                  c_KP9, c_QP9, c_CG9, c_M2S9,
                                  Sl, fwl, bf1l, wf2l);
    } else {
        fused_body<4, 2, 2, 1, 2>(bid - 6400, proj_bf, vt + (size_t)256 * 64 * 224,
                                  fw4, mask, WT, bf1, Wf2, ctxcb,
                                  c_KP4, c_QP4, c_CG4, c_M2S4,
                                  Sl, fwl, bf1l, wf2l);
    }
}

// ---------------------------------------------------------------------------
// Kernel 3 (MFMA, merged both outputs):
// out = LayerNorm( ctx(bf16) @ WdT + bias + resid ) * g + b
// ---------------------------------------------------------------------------
__global__ __launch_bounds__(256, 3) void out_ln2(
    const short* __restrict__ ctxb, const short* __restrict__ ctxcb,
    const short* __restrict__ WT15, const short* __restrict__ WT16,
    const float* __restrict__ bd,   const float* __restrict__ bda,
    const float* __restrict__ X,    const float* __restrict__ HA,
    const float* __restrict__ g0,   const float* __restrict__ be0,
    const float* __restrict__ g1,   const float* __restrict__ be1,
    float* __restrict__ out0,       float* __restrict__ out1)
{
    const int bidx = blockIdx.x;
    const bool sec = bidx >= 400;
    const short* Ab    = sec ? ctxcb : ctxb;
    const short* WTp   = sec ? WT16 : WT15;
    const float* bias  = sec ? bda : bd;
    const float* resid = sec ? HA : X;
    const float* gamma = sec ? g1 : g0;
    const float* beta  = sec ? be1 : be0;
    float* out = sec ? out1 : out0;
    const int m0 = (sec ? bidx - 400 : bidx) * 32;

    __shared__ __align__(16) short As[32 * 264];
    __shared__ float ylds[32][257];
    const int tid = threadIdx.x;
    const int lane = tid & 63, wv = tid >> 6;
    const int l15 = lane & 15, l4 = lane >> 4;

    for (int t = tid; t < 32 * 32; t += 256) {
        int r = t >> 5, c8 = t & 31;
        *(bf16x8*)(As + r * 264 + c8 * 8) = *(const bf16x8*)(Ab + (size_t)(m0 + r) * Dc + c8 * 8);
    }
    __syncthreads();

    const int nb = wv * 64;
    f32x4 acc[2][4];
    #pragma unroll
    for (int mi = 0; mi < 2; ++mi)
        #pragma unroll
        for (int ni = 0; ni < 4; ++ni) acc[mi][ni] = (f32x4){};

    #pragma unroll
    for (int ks = 0; ks < 8; ++ks) {
        bf16x8 bfr[4];
        #pragma unroll
        for (int ni = 0; ni < 4; ++ni)
            bfr[ni] = *(const bf16x8*)(WTp + (size_t)(nb + ni * 16 + l15) * Dc + ks * 32 + l4 * 8);
        #pragma unroll
        for (int mi = 0; mi < 2; ++mi) {
            bf16x8 a = *(const bf16x8*)(As + (mi * 16 + l15) * 264 + ks * 32 + l4 * 8);
            #pragma unroll
            for (int ni = 0; ni < 4; ++ni)
                acc[mi][ni] = mfma16(a, bfr[ni], acc[mi][ni]);
        }
    }

    #pragma unroll
    for (int mi = 0; mi < 2; ++mi) {
        #pragma unroll
        for (int ni = 0; ni < 4; ++ni) {
            int n = nb + ni * 16 + l15;
            float bv = bias[n];
            #pragma unroll
            for (int i = 0; i < 4; ++i) {
                int row = mi * 16 + l4 * 4 + i;
                ylds[row][n] = acc[mi][ni][i] + bv + resid[(size_t)(m0 + row) * Dc + n];
            }
        }
    }
    __syncthreads();

    for (int r = wv * 8; r < wv * 8 + 8; ++r) {
        float v4[4];
        float s = 0.f, s2 = 0.f;
        #pragma unroll
        for (int t4 = 0; t4 < 4; ++t4) {
            float v = ylds[r][t4 * 64 + lane];
            v4[t4] = v;
            s += v; s2 += v * v;
        }
        #pragma unroll
        for (int off = 32; off >= 1; off >>= 1) {
            s  += __shfl_xor(s, off, 64);
            s2 += __shfl_xor(s2, off, 64);
        }
        float m   = s * (1.f / 256.f);
        float var = s2 * (1.f / 256.f) - m * m;
        float rstd = rsqrtf(var + 1e-12f);
        #pragma unroll
        for (int t4 = 0; t4 < 4; ++t4) {
            int ccol = t4 * 64 + lane;
            out[(size_t)(m0 + r) * Dc + ccol] = (v4[t4] - m) * rstd * gamma[ccol] + beta[ccol];
        }
    }
}

// ---------------------------------------------------------------------------
// Launcher
// ---------------------------------------------------------------------------
extern "C" void kernel_launch(void* const* d_in, const int* in_sizes, int n_in,
                              void* d_out, int out_size, void* d_ws, size_t ws_size,
                              hipStream_t stream) {
    const float* X    = (const float*)d_in[0];
    const float* AT   = (const float*)d_in[1];
    const float* P    = (const float*)d_in[2];
    const float* HA   = (const float*)d_in[3];
    const float* mask = (const float*)d_in[4];
    const float* fw   = (const float*)d_in[5];
    const float* fwc  = (const float*)d_in[6];

    const float* Wq   = (const float*)d_in[7];
    const float* bq   = (const float*)d_in[8];
    const float* Wk   = (const float*)d_in[9];
    const float* bk   = (const float*)d_in[10];
    const float* Wv   = (const float*)d_in[11];
    const float* bv   = (const float*)d_in[12];
    const float* Wqp  = (const float*)d_in[13];
    const float* bqp  = (const float*)d_in[14];
    const float* Wkp  = (const float*)d_in[15];
    const float* bkp  = (const float*)d_in[16];
    const float* Waq  = (const float*)d_in[17];
    const float* baq  = (const float*)d_in[18];
    const float* Wak  = (const float*)d_in[19];
    const float* bak  = (const float*)d_in[20];
    const float* Wav  = (const float*)d_in[21];
    const float* bav  = (const float*)d_in[22];
    const float* Wqic = (const float*)d_in[23];
    const float* bqic = (const float*)d_in[24];
    const float* Wqci = (const float*)d_in[25];
    const float* bqci = (const float*)d_in[26];
    const float* Wqpc = (const float*)d_in[27];
    const float* bqpc = (const float*)d_in[28];
    const float* Wqcp = (const float*)d_in[29];
    const float* bqcp = (const float*)d_in[30];
    const float* Wf1  = (const float*)d_in[31];
    const float* bf1  = (const float*)d_in[32];
    const float* Wf2  = (const float*)d_in[33];
    const float* bf2  = (const float*)d_in[34];
    const float* Wd   = (const float*)d_in[35];
    const float* bd   = (const float*)d_in[36];
    const float* ln_g = (const float*)d_in[37];
    const float* ln_b = (const float*)d_in[38];
    const float* Wda  = (const float*)d_in[39];
    const float* bda  = (const float*)d_in[40];
    const float* lna_g= (const float*)d_in[41];
    const float* lna_b= (const float*)d_in[42];

    char* w = (char*)d_ws;
    short* proj_bf = (short*)w;  w += (size_t)NPROJ * NPc * Dc * sizeof(short);
    short* WTall   = (short*)w;  w += (size_t)NWT * Dc * Dc * sizeof(short);
    short* WTf1    = (short*)w;  w += (size_t)224 * 224 * sizeof(short);
    short* inb     = (short*)w;  w += (size_t)4 * NPc * Dc * sizeof(short);
    short* vt      = (short*)w;  w += (size_t)2 * 256 * 64 * 224 * sizeof(short);
    short* ctxb    = (short*)w;  w += (size_t)NPc * Dc * sizeof(short);
    short* ctxcb   = (short*)w;  w += (size_t)NPc * Dc * sizeof(short);

    // input-tensor id per projection: 0=X 1=AT 2=P 3=HA
    const int aid[NPROJ] = {0,0,0,2,2,1,1,3,3,3,0,1,1,3,2};
    const float* Wmat[NWT] = {Wq, Wk, Wv, Wqp, Wkp, Waq, Wak, Waq, Wak, Wav,
                              Wqic, Wqci, Wqcp, Wqcp, Wqpc, Wd, Wda};
    const float* bmat[NPROJ] = {bq, bk, bv, bqp, bkp, baq, bak, baq, bak, bav,
                                bqic, bqci, bqcp, bqcp, bqpc};

    ProjArgsM pm;
    WList wl;
    for (int i = 0; i < NPROJ; i++) {
        pm.A[i]    = inb + (size_t)aid[i] * NPc * Dc;
        pm.bias[i] = bmat[i];
    }
    for (int i = 0; i < NWT; i++) wl.w[i] = Wmat[i];

    // 0. prep (casts + weight transposes), one launch
    prep_kernel<<<13268, 256, 0, stream>>>(X, AT, P, HA, inb, wl, WTall, Wf1, WTf1);

    // 1. projections (MFMA, bf16 in/out, coalesced epilogue)
    proj_mfma<<<dim3(NPc / 64, NPROJ), 256, 0, stream>>>(pm, WTall, proj_bf);

    // 1b. V transpose (iv, hav) -> vt bf16
    vt_kernel<<<512, 256, 0, stream>>>(proj_bf, vt);

    // 2. merged fused attention (256 threads, ctx out in bf16)
    fused12<<<12800, 256, 0, stream>>>(proj_bf, vt, fw, fwc, mask, WTf1, bf1, Wf2, ctxb, ctxcb);

    // 3. output projections + residual + LayerNorm (MFMA), one launch
    out_ln2<<<800, 256, 0, stream>>>(ctxb, ctxcb,
                                     WTall + (size_t)15 * Dc * Dc,
                                     WTall + (size_t)16 * Dc * Dc,
                                     bd, bda, X, HA,
                                     ln_g, ln_b, lna_g, lna_b,
                                     (float*)d_out, (float*)d_out + (size_t)NPc * Dc);
}

// Round 17
// 459.273 us; speedup vs baseline: 1.3281x; 1.0003x over previous
//
#include <hip/hip_runtime.h>
#include <cstddef>

typedef __attribute__((ext_vector_type(8))) short bf16x8;
typedef __attribute__((ext_vector_type(4))) short bf16x4;
typedef __attribute__((ext_vector_type(4))) float f32x4;

constexpr int Bc = 64;
constexpr int Sc = 200;
constexpr int Hc = 4;
constexpr int Dc = 256;
constexpr int HDc = 64;
constexpr int NPc = Bc * Sc;          // 12800 rows
constexpr int NPROJ = 15;
constexpr int NWT   = 17;             // 15 proj weights + Wd + Wda
constexpr int SLD   = 232;            // S row stride (shorts); cols 224-231 hold evw
constexpr float SCALE = 0.125f;       // 1/sqrt(64)

// proj indices
// 0 iq, 1 ik, 2 iv, 3 pq, 4 pk, 5 aq, 6 ak, 7 haq, 8 hak, 9 hav,
// 10 iqc, 11 ciq, 12 cqp, 13 cqp_a, 14 pqc

__constant__ int c_KP9[3]  = {1,6,4};                   // K proj per group
__constant__ int c_QP9[9]  = {0,11,3, 10,5,14, 0,12,3}; // Q proj per (g,k) slot
__constant__ int c_CG9[9]  = {0,3,6, 1,4,7, 2,5,8};     // slot -> channel
__constant__ int c_M2S9[9] = {0,24,48,8,32,56,16,40,64};// channel -> S row base
__constant__ int c_KP4[2]  = {8,4};
__constant__ int c_QP4[4]  = {7,14, 13,3};
__constant__ int c_CG4[4]  = {0,2, 1,3};
__constant__ int c_M2S4[4] = {0,16,8,24};

__device__ __forceinline__ short f2bf(float x) {
    union { float f; unsigned u; } v; v.f = x;
    unsigned r = v.u + 0x7FFFu + ((v.u >> 16) & 1u);
    return (short)(r >> 16);
}
__device__ __forceinline__ float bf2f(short x) {
    union { unsigned u; float f; } v; v.u = ((unsigned)(unsigned short)x) << 16;
    return v.f;
}
__device__ __forceinline__ unsigned cvtpk(float lo, float hi) {
    unsigned r;
    asm("v_cvt_pk_bf16_f32 %0, %1, %2" : "=v"(r) : "v"(lo), "v"(hi));
    return r;
}
__device__ __forceinline__ f32x4 mfma16(bf16x8 a, bf16x8 b, f32x4 c) {
    return __builtin_amdgcn_mfma_f32_16x16x32_bf16(a, b, c, 0, 0, 0);
}

struct ProjArgsM {
    const short* A[NPROJ];      // bf16 input per projection
    const float* bias[NPROJ];
};
struct WList { const float* w[NWT]; };

// ---------------------------------------------------------------------------
// prep: cast_in (blocks 0..12799) + cast_wt (12800..13071) + wf1t (13072..13267)
// ---------------------------------------------------------------------------
__global__ __launch_bounds__(256) void prep_kernel(
    const float* __restrict__ X, const float* __restrict__ AT,
    const float* __restrict__ P, const float* __restrict__ HA,
    short* __restrict__ inb,
    WList wl, short* __restrict__ WTall,
    const float* __restrict__ Wf1, short* __restrict__ WTf1)
{
    __shared__ float tbuf[64][65];
    const int bid = blockIdx.x;
    const int tid = threadIdx.x;

    if (bid < 12800) {
        int ten = bid / 3200, blk = bid - ten * 3200;
        const float* srcs[4] = {X, AT, P, HA};
        const float* src = srcs[ten];
        short* d = inb + (size_t)ten * NPc * Dc;
        int t = blk * 256 + tid;
        float4 v = ((const float4*)src)[t];
        uint2 st;
        st.x = cvtpk(v.x, v.y);
        st.y = cvtpk(v.z, v.w);
        *(uint2*)(d + (size_t)t * 4) = st;
    } else if (bid < 13072) {
        int q = bid - 12800;
        int p = q >> 4, tile = q & 15;
        int k0 = (tile >> 2) * 64, n0 = (tile & 3) * 64;
        const float* W = wl.w[p];
        short* d = WTall + (size_t)p * Dc * Dc;
        for (int i = tid; i < 64 * 64; i += 256) {
            int k = i >> 6, n = i & 63;
            tbuf[k][n] = W[(size_t)(k0 + k) * Dc + n0 + n];
        }
        __syncthreads();
        for (int i = tid; i < 64 * 64; i += 256) {
            int n = i >> 6, k = i & 63;
            d[(size_t)(n0 + n) * Dc + k0 + k] = f2bf(tbuf[k][n]);
        }
    } else {
        int t = (bid - 13072) * 256 + tid;
        if (t < 224 * 224) {
            int j = t / 224, i = t % 224;
            WTf1[t] = (i < Sc && j < Sc) ? f2bf(Wf1[(size_t)i * Sc + j]) : (short)0;
        }
    }
}

// ---------------------------------------------------------------------------
// V transpose: proj_bf[p={2,9}] head strips -> vt[t][(b*4+h)][64][224] bf16
// ---------------------------------------------------------------------------
__global__ __launch_bounds__(256) void vt_kernel(const short* __restrict__ proj_bf,
                                                 short* __restrict__ vt) {
    const int bid = blockIdx.x;
    const int t  = bid >> 8;
    const int bh = bid & 255;
    const int b = bh >> 2, h = bh & 3;
    const int p = t ? 9 : 2;
    const short* src = proj_bf + ((size_t)p * NPc + (size_t)b * Sc) * Dc + h * HDc;
    short* dst = vt + ((size_t)t * 256 + bh) * 64 * 224;
    __shared__ short tile[200][72];
    const int tid = threadIdx.x;
    for (int idx = tid; idx < 200 * 8; idx += 256) {
        int j = idx >> 3, c8 = idx & 7;
        *(bf16x8*)(&tile[j][c8 * 8]) = *(const bf16x8*)(src + (size_t)j * Dc + c8 * 8);
    }
    __syncthreads();
    for (int idx = tid; idx < 64 * 28; idx += 256) {
        int d = idx / 28, c8 = idx % 28;
        bf16x8 o;
        #pragma unroll
        for (int i = 0; i < 8; ++i) {
            int j = c8 * 8 + i;
            o[i] = (j < 200) ? tile[j][d] : (short)0;
        }
        *(bf16x8*)(dst + (size_t)d * 224 + c8 * 8) = o;
    }
}

// ---------------------------------------------------------------------------
// Kernel 1 (MFMA): all 15 projections. C[64 x 256] tile per block. bf16 out.
// B-fragment loads double-buffered across ks (hides L2 latency under MFMAs).
// (256,3) NOT (256,4): pipeline regs ~110-120; a 128-VGPR clamp risks the
// R5/R8 spill trap.
// ---------------------------------------------------------------------------
__global__ __launch_bounds__(256, 3) void proj_mfma(
    ProjArgsM args, const short* __restrict__ WTall, short* __restrict__ proj_bf)
{
    const int p  = blockIdx.y;
    const int m0 = blockIdx.x * 64;
    const short* __restrict__ A   = args.A[p];
    const short* __restrict__ WTp = WTall + (size_t)p * Dc * Dc;
    const float* __restrict__ bias = args.bias[p];
    short* __restrict__ ob = proj_bf + (size_t)p * NPc * Dc;

    __shared__ __align__(16) short As[64 * 280];
    const int tid = threadIdx.x;
    const int lane = tid & 63, w = tid >> 6;
    const int l15 = lane & 15, l4 = lane >> 4;

    for (int t = tid; t < 64 * 32; t += 256) {
        int r = t >> 5, c8 = t & 31;
        *(bf16x8*)(As + r * 280 + c8 * 8) = *(const bf16x8*)(A + (size_t)(m0 + r) * Dc + c8 * 8);
    }
    __syncthreads();

    f32x4 acc[4][4];
    #pragma unroll
    for (int mi = 0; mi < 4; ++mi)
        #pragma unroll
        for (int ni = 0; ni < 4; ++ni) acc[mi][ni] = (f32x4){};

    const int nb = w * 64;
    bf16x8 cur[4], nxt[4];
    #pragma unroll
    for (int ni = 0; ni < 4; ++ni)
        cur[ni] = *(const bf16x8*)(WTp + (size_t)(nb + ni * 16 + l15) * Dc + l4 * 8);

    #pragma unroll
    for (int ks = 0; ks < 8; ++ks) {
        if (ks < 7) {
            #pragma unroll
            for (int ni = 0; ni < 4; ++ni)
                nxt[ni] = *(const bf16x8*)(WTp + (size_t)(nb + ni * 16 + l15) * Dc + (ks + 1) * 32 + l4 * 8);
        }
        #pragma unroll
        for (int mi = 0; mi < 4; ++mi) {
            bf16x8 a = *(const bf16x8*)(As + (mi * 16 + l15) * 280 + ks * 32 + l4 * 8);
            #pragma unroll
            for (int ni = 0; ni < 4; ++ni)
                acc[mi][ni] = mfma16(a, cur[ni], acc[mi][ni]);
        }
        #pragma unroll
        for (int ni = 0; ni < 4; ++ni) cur[ni] = nxt[ni];
    }

    float bv[4];
    #pragma unroll
    for (int ni = 0; ni < 4; ++ni) bv[ni] = bias[nb + ni * 16 + l15];

    __syncthreads();   // all As reads complete before overwrite

    // stage C (bf16) into As: [64 rows][stride 280], cols 0..255
    #pragma unroll
    for (int mi = 0; mi < 4; ++mi) {
        #pragma unroll
        for (int ni = 0; ni < 4; ++ni) {
            int n = nb + ni * 16 + l15;
            int mloc = mi * 16 + l4 * 4;
            #pragma unroll
            for (int i = 0; i < 4; ++i)
                As[(mloc + i) * 280 + n] = f2bf(acc[mi][ni][i] + bv[ni]);
        }
    }
    __syncthreads();

    // coalesced stores: per pass, wave writes 2 rows x 1KB contiguous
    #pragma unroll
    for (int pp = 0; pp < 8; ++pp) {
        int r  = pp * 8 + (tid >> 5);
        int c0 = (tid & 31) * 8;
        *(bf16x8*)(ob + (size_t)(m0 + r) * Dc + c0) = *(const bf16x8*)(As + r * 280 + c0);
    }
}

// ---------------------------------------------------------------------------
// fused body (v9/v12 structure — proven 374 us, VGPR 84, no spills).
// R5/R8/R11/R12: any added live state spills; R15: S-materialization loses.
// ---------------------------------------------------------------------------
template <int CH, int NG, int CPG, int QT, int MT2>
__device__ void fused_body(
    int bid,
    const short* __restrict__ proj_bf,
    const short* __restrict__ vtb,       // [256][64][224] bf16 (per (b,h))
    const float* __restrict__ fw,
    const float* __restrict__ mask,
    const short* __restrict__ WT,
    const float* __restrict__ bf1,
    const float* __restrict__ Wf2,
    short* __restrict__ ctx_out,         // bf16 [NPc][256]
    const int* KP, const int* QP, const int* CG, const int* M2S,
    short* Sl, float* fwl, float* bf1l, float* wf2l)
{
    constexpr int GR    = CPG * 8;       // valid S rows per group
    constexpr int VROWS = NG * GR;       // total valid S rows
    constexpr int SROWS = MT2 * 16;
    constexpr int NW    = 4;

    const int tid = threadIdx.x;
    const int rt  = bid % 25;
    const int h   = (bid / 25) & 3;
    const int b   = bid / 100;
    const int r0  = rt * 8;
    const int lane = tid & 63, wv = tid >> 6;   // wv 0..3
    const int l15 = lane & 15, l4 = lane >> 4;
    const int brow0 = b * Sc + r0;

    // ---- phase 0: zero pad regions of Sl (cols 0..223 only); stage bf1/Wf2; fw
    {
        bf16x8 z = {};
        if constexpr (SROWS > VROWS) {
            for (int t = tid; t < (SROWS - VROWS) * 28; t += 256) {
                int r = VROWS + t / 28, c8 = t % 28;
                *(bf16x8*)(Sl + r * SLD + c8 * 8) = z;
            }
        }
        for (int t = tid; t < VROWS * 3; t += 256) {
            int r = t / 3, c8 = t % 3;
            *(bf16x8*)(Sl + r * SLD + 200 + c8 * 8) = z;
        }
    }
    if (tid < 224) {
        bf1l[tid] = (tid < Sc) ? bf1[tid] : 0.f;
        wf2l[tid] = (tid < Sc) ? Wf2[tid] : 0.f;
    }
    if (tid < CH) fwl[tid] = fw[tid];

    // ---- preload Q A-fragments from global (registers)
    bf16x8 af[NG][QT][2];
    #pragma unroll
    for (int g = 0; g < NG; ++g) {
        #pragma unroll
        for (int t = 0; t < QT; ++t) {
            int sr = t * 16 + l15;
            int kk = (sr < GR) ? (sr >> 3) : 0;
            int rr = (sr < GR) ? (sr & 7) : 0;
            const short* qp = proj_bf + ((size_t)QP[g * CPG + kk] * NPc + brow0 + rr) * Dc + h * HDc;
            #pragma unroll
            for (int ks = 0; ks < 2; ++ks)
                af[g][t][ks] = *(const bf16x8*)(qp + ks * 32 + l4 * 8);
        }
    }
    __syncthreads();

    // ---- scores (pipelined over nt): S[m][j] = fw[c] * (q_m . k_j)
    {
        const short* Kb[NG];
        #pragma unroll
        for (int g = 0; g < NG; ++g)
            Kb[g] = proj_bf + ((size_t)KP[g] * NPc + (size_t)b * Sc) * Dc + h * HDc;

        float fwv[NG][QT];
        #pragma unroll
        for (int g = 0; g < NG; ++g)
            #pragma unroll
            for (int t = 0; t < QT; ++t) {
                int k = t * 2 + (l4 >> 1);
                fwv[g][t] = (k < CPG) ? fwl[CG[g * CPG + k]] : 0.f;
            }

        bf16x8 cur[NG][2];
        int nt = wv;
        {
            int j = nt * 16 + l15;
            #pragma unroll
            for (int g = 0; g < NG; ++g) {
                cur[g][0] = *(const bf16x8*)(Kb[g] + (size_t)j * Dc + l4 * 8);
                cur[g][1] = *(const bf16x8*)(Kb[g] + (size_t)j * Dc + 32 + l4 * 8);
            }
        }
        while (nt < 13) {
            const int ntn = nt + NW;
            bf16x8 nxt[NG][2];
            if (ntn < 13) {
                int j2 = ntn * 16 + l15;
                #pragma unroll
                for (int g = 0; g < NG; ++g) {
                    nxt[g][0] = *(const bf16x8*)(Kb[g] + (size_t)j2 * Dc + l4 * 8);
                    nxt[g][1] = *(const bf16x8*)(Kb[g] + (size_t)j2 * Dc + 32 + l4 * 8);
                }
            }
            const int j = nt * 16 + l15;
            const bool jv = (j < Sc);
            #pragma unroll
            for (int g = 0; g < NG; ++g) {
                #pragma unroll
                for (int t = 0; t < QT; ++t) {
                    f32x4 c = {};
                    c = mfma16(af[g][t][0], cur[g][0], c);
                    c = mfma16(af[g][t][1], cur[g][1], c);
                    int k = t * 2 + (l4 >> 1);
                    if (jv && k < CPG) {
                        int srb = g * GR + t * 16 + l4 * 4;
                        float f = fwv[g][t];
                        unsigned p01 = cvtpk(c[0] * f, c[1] * f);
                        unsigned p23 = cvtpk(c[2] * f, c[3] * f);
                        Sl[(srb + 0) * SLD + j] = (short)p01;
                        Sl[(srb + 1) * SLD + j] = (short)(p01 >> 16);
                        Sl[(srb + 2) * SLD + j] = (short)p23;
                        Sl[(srb + 3) * SLD + j] = (short)(p23 >> 16);
                    }
                }
            }
            #pragma unroll
            for (int g = 0; g < NG; ++g) { cur[g][0] = nxt[g][0]; cur[g][1] = nxt[g][1]; }
            nt = ntn;
        }
    }
    __syncthreads();

    // ---- gate: Y[j][m] via MFMA(A=WT rows j, B=Sl rows m); e[m] partials ->
    //      embedded evw at Sl cols 224..231 (float, slot per wave)
    {
        float epart[MT2];
        #pragma unroll
        for (int mt = 0; mt < MT2; ++mt) epart[mt] = 0.f;

        for (int nt = wv; nt < 13; nt += NW) {
            const int jr = nt * 16 + l15;
            bf16x8 wfrag[7];
            #pragma unroll
            for (int ks = 0; ks < 7; ++ks)
                wfrag[ks] = *(const bf16x8*)(WT + (size_t)jr * 224 + ks * 32 + l4 * 8);
            f32x4 cg[MT2];
            #pragma unroll
            for (int mt = 0; mt < MT2; ++mt) cg[mt] = (f32x4){};
            #pragma unroll
            for (int ks = 0; ks < 7; ++ks) {
                #pragma unroll
                for (int mt = 0; mt < MT2; ++mt) {
                    bf16x8 bb = *(const bf16x8*)(Sl + (mt * 16 + l15) * SLD + ks * 32 + l4 * 8);
                    cg[mt] = mfma16(wfrag[ks], bb, cg[mt]);
                }
            }
            float4 b1 = *(const float4*)(bf1l + nt * 16 + l4 * 4);
            float4 w2 = *(const float4*)(wf2l + nt * 16 + l4 * 4);
            #pragma unroll
            for (int mt = 0; mt < MT2; ++mt) {
                float s = fmaxf(cg[mt][0] + b1.x, 0.f) * w2.x
                        + fmaxf(cg[mt][1] + b1.y, 0.f) * w2.y
                        + fmaxf(cg[mt][2] + b1.z, 0.f) * w2.z
                        + fmaxf(cg[mt][3] + b1.w, 0.f) * w2.w;
                s += __shfl_xor(s, 16, 64);
                s += __shfl_xor(s, 32, 64);
                epart[mt] += s;
            }
        }
        if (l4 == 0) {
            #pragma unroll
            for (int mt = 0; mt < MT2; ++mt)
                *(float*)(Sl + (size_t)(mt * 16 + l15) * SLD + 224 + wv * 2) = epart[mt];
        }
    }
    __syncthreads();

    // ================= wave-local tail: rows ra=wv, rb=wv+4 =================
    const int ra = wv, rb = wv + 4;

    // ---- channel softmax (redundant per wave, register result)
    float wchA[CH], wchB[CH];
    {
        float eA[CH], eB[CH];
        float mxA = -1e30f, mxB = -1e30f;
        #pragma unroll
        for (int c = 0; c < CH; ++c) {
            int m = M2S[c];
            float sA = 0.f, sB = 0.f;
            #pragma unroll
            for (int w = 0; w < NW; ++w) {
                sA += *(const float*)(Sl + (size_t)(m + ra) * SLD + 224 + w * 2);
                sB += *(const float*)(Sl + (size_t)(m + rb) * SLD + 224 + w * 2);
            }
            eA[c] = sA; eB[c] = sB;
            mxA = fmaxf(mxA, sA); mxB = fmaxf(mxB, sB);
        }
        float suA = 0.f, suB = 0.f;
        #pragma unroll
        for (int c = 0; c < CH; ++c) {
            eA[c] = __expf(eA[c] - mxA); suA += eA[c];
            eB[c] = __expf(eB[c] - mxB); suB += eB[c];
        }
        float ivA = 1.f / suA, ivB = 1.f / suB;
        #pragma unroll
        for (int c = 0; c < CH; ++c) { wchA[c] = eA[c] * ivA; wchB[c] = eB[c] * ivB; }
    }

    // ---- gated sum + scale + mask (j-contiguous: lane<50 owns j4..j4+3)
    const bool act = lane < 50;
    const int j4 = lane * 4;
    float vA[4], vB[4];
    if (act) {
        const float* mbase = mask + ((size_t)b * Sc + r0) * Sc;
        float aA[4] = {0.f, 0.f, 0.f, 0.f};
        float aB[4] = {0.f, 0.f, 0.f, 0.f};
        #pragma unroll
        for (int c = 0; c < CH; ++c) {
            bf16x4 sA = *(const bf16x4*)(Sl + (size_t)(M2S[c] + ra) * SLD + j4);
            bf16x4 sB = *(const bf16x4*)(Sl + (size_t)(M2S[c] + rb) * SLD + j4);
            float wA = wchA[c], wB = wchB[c];
            #pragma unroll
            for (int i = 0; i < 4; ++i) {
                aA[i] += wA * bf2f(sA[i]);
                aB[i] += wB * bf2f(sB[i]);
            }
        }
        float4 mA = *(const float4*)(mbase + (size_t)ra * Sc + j4);
        float4 mB = *(const float4*)(mbase + (size_t)rb * Sc + j4);
        vA[0] = aA[0] * SCALE + mA.x; vA[1] = aA[1] * SCALE + mA.y;
        vA[2] = aA[2] * SCALE + mA.z; vA[3] = aA[3] * SCALE + mA.w;
        vB[0] = aB[0] * SCALE + mB.x; vB[1] = aB[1] * SCALE + mB.y;
        vB[2] = aB[2] * SCALE + mB.z; vB[3] = aB[3] * SCALE + mB.w;
    } else {
        #pragma unroll
        for (int i = 0; i < 4; ++i) { vA[i] = -1e30f; vB[i] = -1e30f; }
    }

    // ---- row softmax A (register-resident), p -> Sl row ra (bf16)
    {
        float mx = fmaxf(fmaxf(vA[0], vA[1]), fmaxf(vA[2], vA[3]));
        #pragma unroll
        for (int off = 32; off >= 1; off >>= 1) mx = fmaxf(mx, __shfl_xor(mx, off, 64));
        float p0 = act ? __expf(vA[0] - mx) : 0.f;
        float p1 = act ? __expf(vA[1] - mx) : 0.f;
        float p2 = act ? __expf(vA[2] - mx) : 0.f;
        float p3 = act ? __expf(vA[3] - mx) : 0.f;
        float s = p0 + p1 + p2 + p3;
        #pragma unroll
        for (int off = 32; off >= 1; off >>= 1) s += __shfl_xor(s, off, 64);
        float inv = 1.f / s;
        if (act) {
            uint2 st;
            st.x = cvtpk(p0 * inv, p1 * inv);
            st.y = cvtpk(p2 * inv, p3 * inv);
            *(uint2*)(Sl + (size_t)ra * SLD + j4) = st;
        }
    }
    // ---- row softmax B, p -> Sl row rb (bf16)
    {
        float mx = fmaxf(fmaxf(vB[0], vB[1]), fmaxf(vB[2], vB[3]));
        #pragma unroll
        for (int off = 32; off >= 1; off >>= 1) mx = fmaxf(mx, __shfl_xor(mx, off, 64));
        float p0 = act ? __expf(vB[0] - mx) : 0.f;
        float p1 = act ? __expf(vB[1] - mx) : 0.f;
        float p2 = act ? __expf(vB[2] - mx) : 0.f;
        float p3 = act ? __expf(vB[3] - mx) : 0.f;
        float s = p0 + p1 + p2 + p3;
        #pragma unroll
        for (int off = 32; off >= 1; off >>= 1) s += __shfl_xor(s, off, 64);
        float inv = 1.f / s;
        if (act) {
            uint2 st;
            st.x = cvtpk(p0 * inv, p1 * inv);
            st.y = cvtpk(p2 * inv, p3 * inv);
            *(uint2*)(Sl + (size_t)rb * SLD + j4) = st;
        }
    }
    __syncthreads();

    // ---- PV via MFMA: A = p tile (Sl rows 0..15; 8 valid), B = Vt rows
    {
        const short* vb = vtb + ((size_t)(b * Hc + h) * 64) * 224;
        const int nb = wv * 16;
        f32x4 c0 = {}, c1 = {};
        #pragma unroll
        for (int ks = 0; ks < 7; ks += 2) {
            bf16x8 aa = *(const bf16x8*)(Sl + l15 * SLD + ks * 32 + l4 * 8);
            bf16x8 bb = *(const bf16x8*)(vb + (size_t)(nb + l15) * 224 + ks * 32 + l4 * 8);
            c0 = mfma16(aa, bb, c0);
            if (ks + 1 < 7) {
                bf16x8 aa1 = *(const bf16x8*)(Sl + l15 * SLD + (ks + 1) * 32 + l4 * 8);
                bf16x8 bb1 = *(const bf16x8*)(vb + (size_t)(nb + l15) * 224 + (ks + 1) * 32 + l4 * 8);
                c1 = mfma16(aa1, bb1, c1);
            }
        }
        if (l4 < 2) {
            #pragma unroll
            for (int i = 0; i < 4; ++i) {
                int row = l4 * 4 + i;
                ctx_out[((size_t)(brow0 + row)) * Dc + h * HDc + nb + l15] =
                    f2bf(c0[i] + c1[i]);
            }
        }
    }
}

// ---------------------------------------------------------------------------
// Kernel 2: merged fused attention, 256 threads, XCD-balanced swizzle.
// ---------------------------------------------------------------------------
__global__ __launch_bounds__(256, 3) void fused12(
    const short* __restrict__ proj_bf,
    const short* __restrict__ vt,        // [2][256][64][224]
    const float* __restrict__ fw9,
    const float* __restrict__ fw4,
    const float* __restrict__ mask,
    const short* __restrict__ WT,
    const float* __restrict__ bf1,
    const float* __restrict__ Wf2,
    short* __restrict__ ctxb,
    short* __restrict__ ctxcb)
{
    __shared__ __align__(16) short Sl[80 * SLD];
    __shared__ float fwl[9];
    __shared__ float bf1l[224];
    __shared__ float wf2l[224];

    const int d    = blockIdx.x;          // 0..12799
    const int xcd  = d & 7;
    const int slot = d >> 3;              // 0..1599
    const int chunk = (slot / 25) * 8 + xcd;
    const int pos   = slot % 25;
    const int bid   = chunk * 25 + pos;

    if (bid < 6400) {
        fused_body<9, 3, 3, 2, 5>(bid, proj_bf, vt, fw9, mask, WT, bf1, Wf2, ctxb,
                                  c_KP9, c_QP9, c_CG9, c_M2S9,
                                  Sl, fwl, bf1l, wf2l);
    } else {
        fused_body<4, 2, 2, 1, 2>(bid - 6400, proj_bf, vt + (size_t)256 * 64 * 224,
                                  fw4, mask, WT, bf1, Wf2, ctxcb,
                                  c_KP4, c_QP4, c_CG4, c_M2S4,
                                  Sl, fwl, bf1l, wf2l);
    }
}

// ---------------------------------------------------------------------------
// Kernel 3 (MFMA, merged both outputs):
// out = LayerNorm( ctx(bf16) @ WdT + bias + resid ) * g + b
// B-fragment loads double-buffered across ks.
// ---------------------------------------------------------------------------
__global__ __launch_bounds__(256, 3) void out_ln2(
    const short* __restrict__ ctxb, const short* __restrict__ ctxcb,
    const short* __restrict__ WT15, const short* __restrict__ WT16,
    const float* __restrict__ bd,   const float* __restrict__ bda,
    const float* __restrict__ X,    const float* __restrict__ HA,
    const float* __restrict__ g0,   const float* __restrict__ be0,
    const float* __restrict__ g1,   const float* __restrict__ be1,
    float* __restrict__ out0,       float* __restrict__ out1)
{
    const int bidx = blockIdx.x;
    const bool sec = bidx >= 400;
    const short* Ab    = sec ? ctxcb : ctxb;
    const short* WTp   = sec ? WT16 : WT15;
    const float* bias  = sec ? bda : bd;
    const float* resid = sec ? HA : X;
    const float* gamma = sec ? g1 : g0;
    const float* beta  = sec ? be1 : be0;
    float* out = sec ? out1 : out0;
    const int m0 = (sec ? bidx - 400 : bidx) * 32;

    __shared__ __align__(16) short As[32 * 264];
    __shared__ float ylds[32][257];
    const int tid = threadIdx.x;
    const int lane = tid & 63, wv = tid >> 6;
    const int l15 = lane & 15, l4 = lane >> 4;

    for (int t = tid; t < 32 * 32; t += 256) {
        int r = t >> 5, c8 = t & 31;
        *(bf16x8*)(As + r * 264 + c8 * 8) = *(const bf16x8*)(Ab + (size_t)(m0 + r) * Dc + c8 * 8);
    }
    __syncthreads();

    const int nb = wv * 64;
    f32x4 acc[2][4];
    #pragma unroll
    for (int mi = 0; mi < 2; ++mi)
        #pragma unroll
        for (int ni = 0; ni < 4; ++ni) acc[mi][ni] = (f32x4){};

    bf16x8 cur[4], nxt[4];
    #pragma unroll
    for (int ni = 0; ni < 4; ++ni)
        cur[ni] = *(const bf16x8*)(WTp + (size_t)(nb + ni * 16 + l15) * Dc + l4 * 8);

    #pragma unroll
    for (int ks = 0; ks < 8; ++ks) {
        if (ks < 7) {
            #pragma unroll
            for (int ni = 0; ni < 4; ++ni)
                nxt[ni] = *(const bf16x8*)(WTp + (size_t)(nb + ni * 16 + l15) * Dc + (ks + 1) * 32 + l4 * 8);
        }
        #pragma unroll
        for (int mi = 0; mi < 2; ++mi) {
            bf16x8 a = *(const bf16x8*)(As + (mi * 16 + l15) * 264 + ks * 32 + l4 * 8);
            #pragma unroll
            for (int ni = 0; ni < 4; ++ni)
                acc[mi][ni] = mfma16(a, cur[ni], acc[mi][ni]);
        }
        #pragma unroll
        for (int ni = 0; ni < 4; ++ni) cur[ni] = nxt[ni];
    }

    #pragma unroll
    for (int mi = 0; mi < 2; ++mi) {
        #pragma unroll
        for (int ni = 0; ni < 4; ++ni) {
            int n = nb + ni * 16 + l15;
            float bv = bias[n];
            #pragma unroll
            for (int i = 0; i < 4; ++i) {
                int row = mi * 16 + l4 * 4 + i;
                ylds[row][n] = acc[mi][ni][i] + bv + resid[(size_t)(m0 + row) * Dc + n];
            }
        }
    }
    __syncthreads();

    for (int r = wv * 8; r < wv * 8 + 8; ++r) {
        float v4[4];
        float s = 0.f, s2 = 0.f;
        #pragma unroll
        for (int t4 = 0; t4 < 4; ++t4) {
            float v = ylds[r][t4 * 64 + lane];
            v4[t4] = v;
            s += v; s2 += v * v;
        }
        #pragma unroll
        for (int off = 32; off >= 1; off >>= 1) {
            s  += __shfl_xor(s, off, 64);
            s2 += __shfl_xor(s2, off, 64);
        }
        float m   = s * (1.f / 256.f);
        float var = s2 * (1.f / 256.f) - m * m;
        float rstd = rsqrtf(var + 1e-12f);
        #pragma unroll
        for (int t4 = 0; t4 < 4; ++t4) {
            int ccol = t4 * 64 + lane;
            out[(size_t)(m0 + r) * Dc + ccol] = (v4[t4] - m) * rstd * gamma[ccol] + beta[ccol];
        }
    }
}

// ---------------------------------------------------------------------------
// Launcher
// ---------------------------------------------------------------------------
extern "C" void kernel_launch(void* const* d_in, const int* in_sizes, int n_in,
                              void* d_out, int out_size, void* d_ws, size_t ws_size,
                              hipStream_t stream) {
    const float* X    = (const float*)d_in[0];
    const float* AT   = (const float*)d_in[1];
    const float* P    = (const float*)d_in[2];
    const float* HA   = (const float*)d_in[3];
    const float* mask = (const float*)d_in[4];
    const float* fw   = (const float*)d_in[5];
    const float* fwc  = (const float*)d_in[6];

    const float* Wq   = (const float*)d_in[7];
    const float* bq   = (const float*)d_in[8];
    const float* Wk   = (const float*)d_in[9];
    const float* bk   = (const float*)d_in[10];
    const float* Wv   = (const float*)d_in[11];
    const float* bv   = (const float*)d_in[12];
    const float* Wqp  = (const float*)d_in[13];
    const float* bqp  = (const float*)d_in[14];
    const float* Wkp  = (const float*)d_in[15];
    const float* bkp  = (const float*)d_in[16];
    const float* Waq  = (const float*)d_in[17];
    const float* baq  = (const float*)d_in[18];
    const float* Wak  = (const float*)d_in[19];
    const float* bak  = (const float*)d_in[20];
    const float* Wav  = (const float*)d_in[21];
    const float* bav  = (const float*)d_in[22];
    const float* Wqic = (const float*)d_in[23];
    const float* bqic = (const float*)d_in[24];
    const float* Wqci = (const float*)d_in[25];
    const float* bqci = (const float*)d_in[26];
    const float* Wqpc = (const float*)d_in[27];
    const float* bqpc = (const float*)d_in[28];
    const float* Wqcp = (const float*)d_in[29];
    const float* bqcp = (const float*)d_in[30];
    const float* Wf1  = (const float*)d_in[31];
    const float* bf1  = (const float*)d_in[32];
    const float* Wf2  = (const float*)d_in[33];
    const float* bf2  = (const float*)d_in[34];
    const float* Wd   = (const float*)d_in[35];
    const float* bd   = (const float*)d_in[36];
    const float* ln_g = (const float*)d_in[37];
    const float* ln_b = (const float*)d_in[38];
    const float* Wda  = (const float*)d_in[39];
    const float* bda  = (const float*)d_in[40];
    const float* lna_g= (const float*)d_in[41];
    const float* lna_b= (const float*)d_in[42];

    char* w = (char*)d_ws;
    short* proj_bf = (short*)w;  w += (size_t)NPROJ * NPc * Dc * sizeof(short);
    short* WTall   = (short*)w;  w += (size_t)NWT * Dc * Dc * sizeof(short);
    short* WTf1    = (short*)w;  w += (size_t)224 * 224 * sizeof(short);
    short* inb     = (short*)w;  w += (size_t)4 * NPc * Dc * sizeof(short);
    short* vt      = (short*)w;  w += (size_t)2 * 256 * 64 * 224 * sizeof(short);
    short* ctxb    = (short*)w;  w += (size_t)NPc * Dc * sizeof(short);
    short* ctxcb   = (short*)w;  w += (size_t)NPc * Dc * sizeof(short);

    // input-tensor id per projection: 0=X 1=AT 2=P 3=HA
    const int aid[NPROJ] = {0,0,0,2,2,1,1,3,3,3,0,1,1,3,2};
    const float* Wmat[NWT] = {Wq, Wk, Wv, Wqp, Wkp, Waq, Wak, Waq, Wak, Wav,
                              Wqic, Wqci, Wqcp, Wqcp, Wqpc, Wd, Wda};
    const float* bmat[NPROJ] = {bq, bk, bv, bqp, bkp, baq, bak, baq, bak, bav,
                                bqic, bqci, bqcp, bqcp, bqpc};

    ProjArgsM pm;
    WList wl;
    for (int i = 0; i < NPROJ; i++) {
        pm.A[i]    = inb + (size_t)aid[i] * NPc * Dc;
        pm.bias[i] = bmat[i];
    }
    for (int i = 0; i < NWT; i++) wl.w[i] = Wmat[i];

    // 0. prep (casts + weight transposes), one launch
    prep_kernel<<<13268, 256, 0, stream>>>(X, AT, P, HA, inb, wl, WTall, Wf1, WTf1);

    // 1. projections (MFMA, bf16 in/out, pipelined B loads, coalesced epilogue)
    proj_mfma<<<dim3(NPc / 64, NPROJ), 256, 0, stream>>>(pm, WTall, proj_bf);

    // 1b. V transpose (iv, hav) -> vt bf16
    vt_kernel<<<512, 256, 0, stream>>>(proj_bf, vt);

    // 2. merged fused attention (256 threads, ctx out in bf16)
    fused12<<<12800, 256, 0, stream>>>(proj_bf, vt, fw, fwc, mask, WTf1, bf1, Wf2, ctxb, ctxcb);

    // 3. output projections + residual + LayerNorm (MFMA, pipelined), one launch
    out_ln2<<<800, 256, 0, stream>>>(ctxb, ctxcb,
                                     WTall + (size_t)15 * Dc * Dc,
                                     WTall + (size_t)16 * Dc * Dc,
                                     bd, bda, X, HA,
                                     ln_g, ln_b, lna_g, lna_b,
                                     (float*)d_out, (float*)d_out + (size_t)NPc * Dc);
}

// Round 18
// 458.132 us; speedup vs baseline: 1.3314x; 1.0025x over previous
//
#include <hip/hip_runtime.h>
#include <cstddef>

typedef __attribute__((ext_vector_type(8))) short bf16x8;
typedef __attribute__((ext_vector_type(4))) short bf16x4;
typedef __attribute__((ext_vector_type(4))) float f32x4;

constexpr int Bc = 64;
constexpr int Sc = 200;
constexpr int Hc = 4;
constexpr int Dc = 256;
constexpr int HDc = 64;
constexpr int NPc = Bc * Sc;          // 12800 rows
constexpr int NPROJ = 15;
constexpr int NWT   = 17;             // 15 proj weights + Wd + Wda
constexpr int SLD   = 232;            // S row stride (shorts); cols 224-231 hold evw
constexpr float SCALE = 0.125f;       // 1/sqrt(64)

// proj indices
// 0 iq, 1 ik, 2 iv, 3 pq, 4 pk, 5 aq, 6 ak, 7 haq, 8 hak, 9 hav,
// 10 iqc, 11 ciq, 12 cqp, 13 cqp_a, 14 pqc

__constant__ int c_KP9[3]  = {1,6,4};                   // K proj per group
__constant__ int c_QP9[9]  = {0,11,3, 10,5,14, 0,12,3}; // Q proj per (g,k) slot
__constant__ int c_CG9[9]  = {0,3,6, 1,4,7, 2,5,8};     // slot -> channel
__constant__ int c_M2S9[9] = {0,24,48,8,32,56,16,40,64};// channel -> S row base
__constant__ int c_KP4[2]  = {8,4};
__constant__ int c_QP4[4]  = {7,14, 13,3};
__constant__ int c_CG4[4]  = {0,2, 1,3};
__constant__ int c_M2S4[4] = {0,16,8,24};

__device__ __forceinline__ short f2bf(float x) {
    union { float f; unsigned u; } v; v.f = x;
    unsigned r = v.u + 0x7FFFu + ((v.u >> 16) & 1u);
    return (short)(r >> 16);
}
__device__ __forceinline__ float bf2f(short x) {
    union { unsigned u; float f; } v; v.u = ((unsigned)(unsigned short)x) << 16;
    return v.f;
}
__device__ __forceinline__ unsigned cvtpk(float lo, float hi) {
    unsigned r;
    asm("v_cvt_pk_bf16_f32 %0, %1, %2" : "=v"(r) : "v"(lo), "v"(hi));
    return r;
}
__device__ __forceinline__ f32x4 mfma16(bf16x8 a, bf16x8 b, f32x4 c) {
    return __builtin_amdgcn_mfma_f32_16x16x32_bf16(a, b, c, 0, 0, 0);
}

struct ProjArgsM {
    const short* A[NPROJ];      // bf16 input per projection
    const float* bias[NPROJ];
};
struct WList { const float* w[NWT]; };

// ---------------------------------------------------------------------------
// prep: cast_in (blocks 0..12799) + cast_wt (12800..13071) + wf1t (13072..13267)
// ---------------------------------------------------------------------------
__global__ __launch_bounds__(256) void prep_kernel(
    const float* __restrict__ X, const float* __restrict__ AT,
    const float* __restrict__ P, const float* __restrict__ HA,
    short* __restrict__ inb,
    WList wl, short* __restrict__ WTall,
    const float* __restrict__ Wf1, short* __restrict__ WTf1)
{
    __shared__ float tbuf[64][65];
    const int bid = blockIdx.x;
    const int tid = threadIdx.x;

    if (bid < 12800) {
        int ten = bid / 3200, blk = bid - ten * 3200;
        const float* srcs[4] = {X, AT, P, HA};
        const float* src = srcs[ten];
        short* d = inb + (size_t)ten * NPc * Dc;
        int t = blk * 256 + tid;
        float4 v = ((const float4*)src)[t];
        uint2 st;
        st.x = cvtpk(v.x, v.y);
        st.y = cvtpk(v.z, v.w);
        *(uint2*)(d + (size_t)t * 4) = st;
    } else if (bid < 13072) {
        int q = bid - 12800;
        int p = q >> 4, tile = q & 15;
        int k0 = (tile >> 2) * 64, n0 = (tile & 3) * 64;
        const float* W = wl.w[p];
        short* d = WTall + (size_t)p * Dc * Dc;
        for (int i = tid; i < 64 * 64; i += 256) {
            int k = i >> 6, n = i & 63;
            tbuf[k][n] = W[(size_t)(k0 + k) * Dc + n0 + n];
        }
        __syncthreads();
        for (int i = tid; i < 64 * 64; i += 256) {
            int n = i >> 6, k = i & 63;
            d[(size_t)(n0 + n) * Dc + k0 + k] = f2bf(tbuf[k][n]);
        }
    } else {
        int t = (bid - 13072) * 256 + tid;
        if (t < 224 * 224) {
            int j = t / 224, i = t % 224;
            WTf1[t] = (i < Sc && j < Sc) ? f2bf(Wf1[(size_t)i * Sc + j]) : (short)0;
        }
    }
}

// ---------------------------------------------------------------------------
// V transpose: proj_bf[p={2,9}] head strips -> vt[t][(b*4+h)][64][224] bf16
// ---------------------------------------------------------------------------
__global__ __launch_bounds__(256) void vt_kernel(const short* __restrict__ proj_bf,
                                                 short* __restrict__ vt) {
    const int bid = blockIdx.x;
    const int t  = bid >> 8;
    const int bh = bid & 255;
    const int b = bh >> 2, h = bh & 3;
    const int p = t ? 9 : 2;
    const short* src = proj_bf + ((size_t)p * NPc + (size_t)b * Sc) * Dc + h * HDc;
    short* dst = vt + ((size_t)t * 256 + bh) * 64 * 224;
    __shared__ short tile[200][72];
    const int tid = threadIdx.x;
    for (int idx = tid; idx < 200 * 8; idx += 256) {
        int j = idx >> 3, c8 = idx & 7;
        *(bf16x8*)(&tile[j][c8 * 8]) = *(const bf16x8*)(src + (size_t)j * Dc + c8 * 8);
    }
    __syncthreads();
    for (int idx = tid; idx < 64 * 28; idx += 256) {
        int d = idx / 28, c8 = idx % 28;
        bf16x8 o;
        #pragma unroll
        for (int i = 0; i < 8; ++i) {
            int j = c8 * 8 + i;
            o[i] = (j < 200) ? tile[j][d] : (short)0;
        }
        *(bf16x8*)(dst + (size_t)d * 224 + c8 * 8) = o;
    }
}

// ---------------------------------------------------------------------------
// Kernel 1 (MFMA): all 15 projections. C[64 x 256] tile per block. bf16 out.
// B-fragment loads double-buffered across ks (hides L2 latency under MFMAs).
// (256,3) NOT (256,4): pipeline regs ~110-120; a 128-VGPR clamp risks the
// R5/R8 spill trap.
// ---------------------------------------------------------------------------
__global__ __launch_bounds__(256, 3) void proj_mfma(
    ProjArgsM args, const short* __restrict__ WTall, short* __restrict__ proj_bf)
{
    const int p  = blockIdx.y;
    const int m0 = blockIdx.x * 64;
    const short* __restrict__ A   = args.A[p];
    const short* __restrict__ WTp = WTall + (size_t)p * Dc * Dc;
    const float* __restrict__ bias = args.bias[p];
    short* __restrict__ ob = proj_bf + (size_t)p * NPc * Dc;

    __shared__ __align__(16) short As[64 * 280];
    const int tid = threadIdx.x;
    const int lane = tid & 63, w = tid >> 6;
    const int l15 = lane & 15, l4 = lane >> 4;

    for (int t = tid; t < 64 * 32; t += 256) {
        int r = t >> 5, c8 = t & 31;
        *(bf16x8*)(As + r * 280 + c8 * 8) = *(const bf16x8*)(A + (size_t)(m0 + r) * Dc + c8 * 8);
    }
    __syncthreads();

    f32x4 acc[4][4];
    #pragma unroll
    for (int mi = 0; mi < 4; ++mi)
        #pragma unroll
        for (int ni = 0; ni < 4; ++ni) acc[mi][ni] = (f32x4){};

    const int nb = w * 64;
    bf16x8 cur[4], nxt[4];
    #pragma unroll
    for (int ni = 0; ni < 4; ++ni)
        cur[ni] = *(const bf16x8*)(WTp + (size_t)(nb + ni * 16 + l15) * Dc + l4 * 8);

    #pragma unroll
    for (int ks = 0; ks < 8; ++ks) {
        if (ks < 7) {
            #pragma unroll
            for (int ni = 0; ni < 4; ++ni)
                nxt[ni] = *(const bf16x8*)(WTp + (size_t)(nb + ni * 16 + l15) * Dc + (ks + 1) * 32 + l4 * 8);
        }
        #pragma unroll
        for (int mi = 0; mi < 4; ++mi) {
            bf16x8 a = *(const bf16x8*)(As + (mi * 16 + l15) * 280 + ks * 32 + l4 * 8);
            #pragma unroll
            for (int ni = 0; ni < 4; ++ni)
                acc[mi][ni] = mfma16(a, cur[ni], acc[mi][ni]);
        }
        #pragma unroll
        for (int ni = 0; ni < 4; ++ni) cur[ni] = nxt[ni];
    }

    float bv[4];
    #pragma unroll
    for (int ni = 0; ni < 4; ++ni) bv[ni] = bias[nb + ni * 16 + l15];

    __syncthreads();   // all As reads complete before overwrite

    // stage C (bf16) into As: [64 rows][stride 280], cols 0..255
    #pragma unroll
    for (int mi = 0; mi < 4; ++mi) {
        #pragma unroll
        for (int ni = 0; ni < 4; ++ni) {
            int n = nb + ni * 16 + l15;
            int mloc = mi * 16 + l4 * 4;
            #pragma unroll
            for (int i = 0; i < 4; ++i)
                As[(mloc + i) * 280 + n] = f2bf(acc[mi][ni][i] + bv[ni]);
        }
    }
    __syncthreads();

    // coalesced stores: per pass, wave writes 2 rows x 1KB contiguous
    #pragma unroll
    for (int pp = 0; pp < 8; ++pp) {
        int r  = pp * 8 + (tid >> 5);
        int c0 = (tid & 31) * 8;
        *(bf16x8*)(ob + (size_t)(m0 + r) * Dc + c0) = *(const bf16x8*)(As + r * 280 + c0);
    }
}

// ---------------------------------------------------------------------------
// fused body (v9/v12 structure — proven 374 us, VGPR 84, no spills).
// R5/R8/R11/R12: any added live state spills; R15: S-materialization loses.
// ---------------------------------------------------------------------------
template <int CH, int NG, int CPG, int QT, int MT2>
__device__ void fused_body(
    int bid,
    const short* __restrict__ proj_bf,
    const short* __restrict__ vtb,       // [256][64][224] bf16 (per (b,h))
    const float* __restrict__ fw,
    const float* __restrict__ mask,
    const short* __restrict__ WT,
    const float* __restrict__ bf1,
    const float* __restrict__ Wf2,
    short* __restrict__ ctx_out,         // bf16 [NPc][256]
    const int* KP, const int* QP, const int* CG, const int* M2S,
    short* Sl, float* fwl, float* bf1l, float* wf2l)
{
    constexpr int GR    = CPG * 8;       // valid S rows per group
    constexpr int VROWS = NG * GR;       // total valid S rows
    constexpr int SROWS = MT2 * 16;
    constexpr int NW    = 4;

    const int tid = threadIdx.x;
    const int rt  = bid % 25;
    const int h   = (bid / 25) & 3;
    const int b   = bid / 100;
    const int r0  = rt * 8;
    const int lane = tid & 63, wv = tid >> 6;   // wv 0..3
    const int l15 = lane & 15, l4 = lane >> 4;
    const int brow0 = b * Sc + r0;

    // ---- phase 0: zero pad regions of Sl (cols 0..223 only); stage bf1/Wf2; fw
    {
        bf16x8 z = {};
        if constexpr (SROWS > VROWS) {
            for (int t = tid; t < (SROWS - VROWS) * 28; t += 256) {
                int r = VROWS + t / 28, c8 = t % 28;
                *(bf16x8*)(Sl + r * SLD + c8 * 8) = z;
            }
        }
        for (int t = tid; t < VROWS * 3; t += 256) {
            int r = t / 3, c8 = t % 3;
            *(bf16x8*)(Sl + r * SLD + 200 + c8 * 8) = z;
        }
    }
    if (tid < 224) {
        bf1l[tid] = (tid < Sc) ? bf1[tid] : 0.f;
        wf2l[tid] = (tid < Sc) ? Wf2[tid] : 0.f;
    }
    if (tid < CH) fwl[tid] = fw[tid];

    // ---- preload Q A-fragments from global (registers)
    bf16x8 af[NG][QT][2];
    #pragma unroll
    for (int g = 0; g < NG; ++g) {
        #pragma unroll
        for (int t = 0; t < QT; ++t) {
            int sr = t * 16 + l15;
            int kk = (sr < GR) ? (sr >> 3) : 0;
            int rr = (sr < GR) ? (sr & 7) : 0;
            const short* qp = proj_bf + ((size_t)QP[g * CPG + kk] * NPc + brow0 + rr) * Dc + h * HDc;
            #pragma unroll
            for (int ks = 0; ks < 2; ++ks)
                af[g][t][ks] = *(const bf16x8*)(qp + ks * 32 + l4 * 8);
        }
    }
    __syncthreads();

    // ---- scores (pipelined over nt): S[m][j] = fw[c] * (q_m . k_j)
    {
        const short* Kb[NG];
        #pragma unroll
        for (int g = 0; g < NG; ++g)
            Kb[g] = proj_bf + ((size_t)KP[g] * NPc + (size_t)b * Sc) * Dc + h * HDc;

        float fwv[NG][QT];
        #pragma unroll
        for (int g = 0; g < NG; ++g)
            #pragma unroll
            for (int t = 0; t < QT; ++t) {
                int k = t * 2 + (l4 >> 1);
                fwv[g][t] = (k < CPG) ? fwl[CG[g * CPG + k]] : 0.f;
            }

        bf16x8 cur[NG][2];
        int nt = wv;
        {
            int j = nt * 16 + l15;
            #pragma unroll
            for (int g = 0; g < NG; ++g) {
                cur[g][0] = *(const bf16x8*)(Kb[g] + (size_t)j * Dc + l4 * 8);
                cur[g][1] = *(const bf16x8*)(Kb[g] + (size_t)j * Dc + 32 + l4 * 8);
            }
        }
        while (nt < 13) {
            const int ntn = nt + NW;
            bf16x8 nxt[NG][2];
            if (ntn < 13) {
                int j2 = ntn * 16 + l15;
                #pragma unroll
                for (int g = 0; g < NG; ++g) {
                    nxt[g][0] = *(const bf16x8*)(Kb[g] + (size_t)j2 * Dc + l4 * 8);
                    nxt[g][1] = *(const bf16x8*)(Kb[g] + (size_t)j2 * Dc + 32 + l4 * 8);
                }
            }
            const int j = nt * 16 + l15;
            const bool jv = (j < Sc);
            #pragma unroll
            for (int g = 0; g < NG; ++g) {
                #pragma unroll
                for (int t = 0; t < QT; ++t) {
                    f32x4 c = {};
                    c = mfma16(af[g][t][0], cur[g][0], c);
                    c = mfma16(af[g][t][1], cur[g][1], c);
                    int k = t * 2 + (l4 >> 1);
                    if (jv && k < CPG) {
                        int srb = g * GR + t * 16 + l4 * 4;
                        float f = fwv[g][t];
                        unsigned p01 = cvtpk(c[0] * f, c[1] * f);
                        unsigned p23 = cvtpk(c[2] * f, c[3] * f);
                        Sl[(srb + 0) * SLD + j] = (short)p01;
                        Sl[(srb + 1) * SLD + j] = (short)(p01 >> 16);
                        Sl[(srb + 2) * SLD + j] = (short)p23;
                        Sl[(srb + 3) * SLD + j] = (short)(p23 >> 16);
                    }
                }
            }
            #pragma unroll
            for (int g = 0; g < NG; ++g) { cur[g][0] = nxt[g][0]; cur[g][1] = nxt[g][1]; }
            nt = ntn;
        }
    }
    __syncthreads();

    // ---- gate: Y[j][m] via MFMA(A=WT rows j, B=Sl rows m); e[m] partials ->
    //      embedded evw at Sl cols 224..231 (float, slot per wave)
    {
        float epart[MT2];
        #pragma unroll
        for (int mt = 0; mt < MT2; ++mt) epart[mt] = 0.f;

        for (int nt = wv; nt < 13; nt += NW) {
            const int jr = nt * 16 + l15;
            bf16x8 wfrag[7];
            #pragma unroll
            for (int ks = 0; ks < 7; ++ks)
                wfrag[ks] = *(const bf16x8*)(WT + (size_t)jr * 224 + ks * 32 + l4 * 8);
            f32x4 cg[MT2];
            #pragma unroll
            for (int mt = 0; mt < MT2; ++mt) cg[mt] = (f32x4){};
            #pragma unroll
            for (int ks = 0; ks < 7; ++ks) {
                #pragma unroll
                for (int mt = 0; mt < MT2; ++mt) {
                    bf16x8 bb = *(const bf16x8*)(Sl + (mt * 16 + l15) * SLD + ks * 32 + l4 * 8);
                    cg[mt] = mfma16(wfrag[ks], bb, cg[mt]);
                }
            }
            float4 b1 = *(const float4*)(bf1l + nt * 16 + l4 * 4);
            float4 w2 = *(const float4*)(wf2l + nt * 16 + l4 * 4);
            #pragma unroll
            for (int mt = 0; mt < MT2; ++mt) {
                float s = fmaxf(cg[mt][0] + b1.x, 0.f) * w2.x
                        + fmaxf(cg[mt][1] + b1.y, 0.f) * w2.y
                        + fmaxf(cg[mt][2] + b1.z, 0.f) * w2.z
                        + fmaxf(cg[mt][3] + b1.w, 0.f) * w2.w;
                s += __shfl_xor(s, 16, 64);
                s += __shfl_xor(s, 32, 64);
                epart[mt] += s;
            }
        }
        if (l4 == 0) {
            #pragma unroll
            for (int mt = 0; mt < MT2; ++mt)
                *(float*)(Sl + (size_t)(mt * 16 + l15) * SLD + 224 + wv * 2) = epart[mt];
        }
    }
    __syncthreads();

    // ================= wave-local tail: rows ra=wv, rb=wv+4 =================
    const int ra = wv, rb = wv + 4;

    // ---- channel softmax (redundant per wave, register result)
    float wchA[CH], wchB[CH];
    {
        float eA[CH], eB[CH];
        float mxA = -1e30f, mxB = -1e30f;
        #pragma unroll
        for (int c = 0; c < CH; ++c) {
            int m = M2S[c];
            float sA = 0.f, sB = 0.f;
            #pragma unroll
            for (int w = 0; w < NW; ++w) {
                sA += *(const float*)(Sl + (size_t)(m + ra) * SLD + 224 + w * 2);
                sB += *(const float*)(Sl + (size_t)(m + rb) * SLD + 224 + w * 2);
            }
            eA[c] = sA; eB[c] = sB;
            mxA = fmaxf(mxA, sA); mxB = fmaxf(mxB, sB);
        }
        float suA = 0.f, suB = 0.f;
        #pragma unroll
        for (int c = 0; c < CH; ++c) {
            eA[c] = __expf(eA[c] - mxA); suA += eA[c];
            eB[c] = __expf(eB[c] - mxB); suB += eB[c];
        }
        float ivA = 1.f / suA, ivB = 1.f / suB;
        #pragma unroll
        for (int c = 0; c < CH; ++c) { wchA[c] = eA[c] * ivA; wchB[c] = eB[c] * ivB; }
    }

    // ---- gated sum + scale + mask (j-contiguous: lane<50 owns j4..j4+3)
    const bool act = lane < 50;
    const int j4 = lane * 4;
    float vA[4], vB[4];
    if (act) {
        const float* mbase = mask + ((size_t)b * Sc + r0) * Sc;
        float aA[4] = {0.f, 0.f, 0.f, 0.f};
        float aB[4] = {0.f, 0.f, 0.f, 0.f};
        #pragma unroll
        for (int c = 0; c < CH; ++c) {
            bf16x4 sA = *(const bf16x4*)(Sl + (size_t)(M2S[c] + ra) * SLD + j4);
            bf16x4 sB = *(const bf16x4*)(Sl + (size_t)(M2S[c] + rb) * SLD + j4);
            float wA = wchA[c], wB = wchB[c];
            #pragma unroll
            for (int i = 0; i < 4; ++i) {
                aA[i] += wA * bf2f(sA[i]);
                aB[i] += wB * bf2f(sB[i]);
            }
        }
        float4 mA = *(const float4*)(mbase + (size_t)ra * Sc + j4);
        float4 mB = *(const float4*)(mbase + (size_t)rb * Sc + j4);
        vA[0] = aA[0] * SCALE + mA.x; vA[1] = aA[1] * SCALE + mA.y;
        vA[2] = aA[2] * SCALE + mA.z; vA[3] = aA[3] * SCALE + mA.w;
        vB[0] = aB[0] * SCALE + mB.x; vB[1] = aB[1] * SCALE + mB.y;
        vB[2] = aB[2] * SCALE + mB.z; vB[3] = aB[3] * SCALE + mB.w;
    } else {
        #pragma unroll
        for (int i = 0; i < 4; ++i) { vA[i] = -1e30f; vB[i] = -1e30f; }
    }

    // ---- row softmax A (register-resident), p -> Sl row ra (bf16)
    {
        float mx = fmaxf(fmaxf(vA[0], vA[1]), fmaxf(vA[2], vA[3]));
        #pragma unroll
        for (int off = 32; off >= 1; off >>= 1) mx = fmaxf(mx, __shfl_xor(mx, off, 64));
        float p0 = act ? __expf(vA[0] - mx) : 0.f;
        float p1 = act ? __expf(vA[1] - mx) : 0.f;
        float p2 = act ? __expf(vA[2] - mx) : 0.f;
        float p3 = act ? __expf(vA[3] - mx) : 0.f;
        float s = p0 + p1 + p2 + p3;
        #pragma unroll
        for (int off = 32; off >= 1; off >>= 1) s += __shfl_xor(s, off, 64);
        float inv = 1.f / s;
        if (act) {
            uint2 st;
            st.x = cvtpk(p0 * inv, p1 * inv);
            st.y = cvtpk(p2 * inv, p3 * inv);
            *(uint2*)(Sl + (size_t)ra * SLD + j4) = st;
        }
    }
    // ---- row softmax B, p -> Sl row rb (bf16)
    {
        float mx = fmaxf(fmaxf(vB[0], vB[1]), fmaxf(vB[2], vB[3]));
        #pragma unroll
        for (int off = 32; off >= 1; off >>= 1) mx = fmaxf(mx, __shfl_xor(mx, off, 64));
        float p0 = act ? __expf(vB[0] - mx) : 0.f;
        float p1 = act ? __expf(vB[1] - mx) : 0.f;
        float p2 = act ? __expf(vB[2] - mx) : 0.f;
        float p3 = act ? __expf(vB[3] - mx) : 0.f;
        float s = p0 + p1 + p2 + p3;
        #pragma unroll
        for (int off = 32; off >= 1; off >>= 1) s += __shfl_xor(s, off, 64);
        float inv = 1.f / s;
        if (act) {
            uint2 st;
            st.x = cvtpk(p0 * inv, p1 * inv);
            st.y = cvtpk(p2 * inv, p3 * inv);
            *(uint2*)(Sl + (size_t)rb * SLD + j4) = st;
        }
    }
    __syncthreads();

    // ---- PV via MFMA: A = p tile (Sl rows 0..15; 8 valid), B = Vt rows
    {
        const short* vb = vtb + ((size_t)(b * Hc + h) * 64) * 224;
        const int nb = wv * 16;
        f32x4 c0 = {}, c1 = {};
        #pragma unroll
        for (int ks = 0; ks < 7; ks += 2) {
            bf16x8 aa = *(const bf16x8*)(Sl + l15 * SLD + ks * 32 + l4 * 8);
            bf16x8 bb = *(const bf16x8*)(vb + (size_t)(nb + l15) * 224 + ks * 32 + l4 * 8);
            c0 = mfma16(aa, bb, c0);
            if (ks + 1 < 7) {
                bf16x8 aa1 = *(const bf16x8*)(Sl + l15 * SLD + (ks + 1) * 32 + l4 * 8);
                bf16x8 bb1 = *(const bf16x8*)(vb + (size_t)(nb + l15) * 224 + (ks + 1) * 32 + l4 * 8);
                c1 = mfma16(aa1, bb1, c1);
            }
        }
        if (l4 < 2) {
            #pragma unroll
            for (int i = 0; i < 4; ++i) {
                int row = l4 * 4 + i;
                ctx_out[((size_t)(brow0 + row)) * Dc + h * HDc + nb + l15] =
                    f2bf(c0[i] + c1[i]);
            }
        }
    }
}

// ---------------------------------------------------------------------------
// Kernel 2: merged fused attention, 256 threads, XCD-balanced swizzle.
// ---------------------------------------------------------------------------
__global__ __launch_bounds__(256, 3) void fused12(
    const short* __restrict__ proj_bf,
    const short* __restrict__ vt,        // [2][256][64][224]
    const float* __restrict__ fw9,
    const float* __restrict__ fw4,
    const float* __restrict__ mask,
    const short* __restrict__ WT,
    const float* __restrict__ bf1,
    const float* __restrict__ Wf2,
    short* __restrict__ ctxb,
    short* __restrict__ ctxcb)
{
    __shared__ __align__(16) short Sl[80 * SLD];
    __shared__ float fwl[9];
    __shared__ float bf1l[224];
    __shared__ float wf2l[224];

    const int d    = blockIdx.x;          // 0..12799
    const int xcd  = d & 7;
    const int slot = d >> 3;              // 0..1599
    const int chunk = (slot / 25) * 8 + xcd;
    const int pos   = slot % 25;
    const int bid   = chunk * 25 + pos;

    if (bid < 6400) {
        fused_body<9, 3, 3, 2, 5>(bid, proj_bf, vt, fw9, mask, WT, bf1, Wf2, ctxb,
                                  c_KP9, c_QP9, c_CG9, c_M2S9,
                                  Sl, fwl, bf1l, wf2l);
    } else {
        fused_body<4, 2, 2, 1, 2>(bid - 6400, proj_bf, vt + (size_t)256 * 64 * 224,
                                  fw4, mask, WT, bf1, Wf2, ctxcb,
                                  c_KP4, c_QP4, c_CG4, c_M2S4,
                                  Sl, fwl, bf1l, wf2l);
    }
}

// ---------------------------------------------------------------------------
// Kernel 3 (MFMA, merged both outputs):
// out = LayerNorm( ctx(bf16) @ WdT + bias + resid ) * g + b
// B-fragment loads double-buffered across ks.
// ---------------------------------------------------------------------------
__global__ __launch_bounds__(256, 3) void out_ln2(
    const short* __restrict__ ctxb, const short* __restrict__ ctxcb,
    const short* __restrict__ WT15, const short* __restrict__ WT16,
    const float* __restrict__ bd,   const float* __restrict__ bda,
    const float* __restrict__ X,    const float* __restrict__ HA,
    const float* __restrict__ g0,   const float* __restrict__ be0,
    const float* __restrict__ g1,   const float* __restrict__ be1,
    float* __restrict__ out0,       float* __restrict__ out1)
{
    const int bidx = blockIdx.x;
    const bool sec = bidx >= 400;
    const short* Ab    = sec ? ctxcb : ctxb;
    const short* WTp   = sec ? WT16 : WT15;
    const float* bias  = sec ? bda : bd;
    const float* resid = sec ? HA : X;
    const float* gamma = sec ? g1 : g0;
    const float* beta  = sec ? be1 : be0;
    float* out = sec ? out1 : out0;
    const int m0 = (sec ? bidx - 400 : bidx) * 32;

    __shared__ __align__(16) short As[32 * 264];
    __shared__ float ylds[32][257];
    const int tid = threadIdx.x;
    const int lane = tid & 63, wv = tid >> 6;
    const int l15 = lane & 15, l4 = lane >> 4;

    for (int t = tid; t < 32 * 32; t += 256) {
        int r = t >> 5, c8 = t & 31;
        *(bf16x8*)(As + r * 264 + c8 * 8) = *(const bf16x8*)(Ab + (size_t)(m0 + r) * Dc + c8 * 8);
    }
    __syncthreads();

    const int nb = wv * 64;
    f32x4 acc[2][4];
    #pragma unroll
    for (int mi = 0; mi < 2; ++mi)
        #pragma unroll
        for (int ni = 0; ni < 4; ++ni) acc[mi][ni] = (f32x4){};

    bf16x8 cur[4], nxt[4];
    #pragma unroll
    for (int ni = 0; ni < 4; ++ni)
        cur[ni] = *(const bf16x8*)(WTp + (size_t)(nb + ni * 16 + l15) * Dc + l4 * 8);

    #pragma unroll
    for (int ks = 0; ks < 8; ++ks) {
        if (ks < 7) {
            #pragma unroll
            for (int ni = 0; ni < 4; ++ni)
                nxt[ni] = *(const bf16x8*)(WTp + (size_t)(nb + ni * 16 + l15) * Dc + (ks + 1) * 32 + l4 * 8);
        }
        #pragma unroll
        for (int mi = 0; mi < 2; ++mi) {
            bf16x8 a = *(const bf16x8*)(As + (mi * 16 + l15) * 264 + ks * 32 + l4 * 8);
            #pragma unroll
            for (int ni = 0; ni < 4; ++ni)
                acc[mi][ni] = mfma16(a, cur[ni], acc[mi][ni]);
        }
        #pragma unroll
        for (int ni = 0; ni < 4; ++ni) cur[ni] = nxt[ni];
    }

    #pragma unroll
    for (int mi = 0; mi < 2; ++mi) {
        #pragma unroll
        for (int ni = 0; ni < 4; ++ni) {
            int n = nb + ni * 16 + l15;
            float bv = bias[n];
            #pragma unroll
            for (int i = 0; i < 4; ++i) {
                int row = mi * 16 + l4 * 4 + i;
                ylds[row][n] = acc[mi][ni][i] + bv + resid[(size_t)(m0 + row) * Dc + n];
            }
        }
    }
    __syncthreads();

    for (int r = wv * 8; r < wv * 8 + 8; ++r) {
        float v4[4];
        float s = 0.f, s2 = 0.f;
        #pragma unroll
        for (int t4 = 0; t4 < 4; ++t4) {
            float v = ylds[r][t4 * 64 + lane];
            v4[t4] = v;
            s += v; s2 += v * v;
        }
        #pragma unroll
        for (int off = 32; off >= 1; off >>= 1) {
            s  += __shfl_xor(s, off, 64);
            s2 += __shfl_xor(s2, off, 64);
        }
        float m   = s * (1.f / 256.f);
        float var = s2 * (1.f / 256.f) - m * m;
        float rstd = rsqrtf(var + 1e-12f);
        #pragma unroll
        for (int t4 = 0; t4 < 4; ++t4) {
            int ccol = t4 * 64 + lane;
            out[(size_t)(m0 + r) * Dc + ccol] = (v4[t4] - m) * rstd * gamma[ccol] + beta[ccol];
        }
    }
}

// ---------------------------------------------------------------------------
// Launcher
// ---------------------------------------------------------------------------
extern "C" void kernel_launch(void* const* d_in, const int* in_sizes, int n_in,
                              void* d_out, int out_size, void* d_ws, size_t ws_size,
                              hipStream_t stream) {
    const float* X    = (const float*)d_in[0];
    const float* AT   = (const float*)d_in[1];
    const float* P    = (const float*)d_in[2];
    const float* HA   = (const float*)d_in[3];
    const float* mask = (const float*)d_in[4];
    const float* fw   = (const float*)d_in[5];
    const float* fwc  = (const float*)d_in[6];

    const float* Wq   = (const float*)d_in[7];
    const float* bq   = (const float*)d_in[8];
    const float* Wk   = (const float*)d_in[9];
    const float* bk   = (const float*)d_in[10];
    const float* Wv   = (const float*)d_in[11];
    const float* bv   = (const float*)d_in[12];
    const float* Wqp  = (const float*)d_in[13];
    const float* bqp  = (const float*)d_in[14];
    const float* Wkp  = (const float*)d_in[15];
    const float* bkp  = (const float*)d_in[16];
    const float* Waq  = (const float*)d_in[17];
    const float* baq  = (const float*)d_in[18];
    const float* Wak  = (const float*)d_in[19];
    const float* bak  = (const float*)d_in[20];
    const float* Wav  = (const float*)d_in[21];
    const float* bav  = (const float*)d_in[22];
    const float* Wqic = (const float*)d_in[23];
    const float* bqic = (const float*)d_in[24];
    const float* Wqci = (const float*)d_in[25];
    const float* bqci = (const float*)d_in[26];
    const float* Wqpc = (const float*)d_in[27];
    const float* bqpc = (const float*)d_in[28];
    const float* Wqcp = (const float*)d_in[29];
    const float* bqcp = (const float*)d_in[30];
    const float* Wf1  = (const float*)d_in[31];
    const float* bf1  = (const float*)d_in[32];
    const float* Wf2  = (const float*)d_in[33];
    const float* bf2  = (const float*)d_in[34];
    const float* Wd   = (const float*)d_in[35];
    const float* bd   = (const float*)d_in[36];
    const float* ln_g = (const float*)d_in[37];
    const float* ln_b = (const float*)d_in[38];
    const float* Wda  = (const float*)d_in[39];
    const float* bda  = (const float*)d_in[40];
    const float* lna_g= (const float*)d_in[41];
    const float* lna_b= (const float*)d_in[42];

    char* w = (char*)d_ws;
    short* proj_bf = (short*)w;  w += (size_t)NPROJ * NPc * Dc * sizeof(short);
    short* WTall   = (short*)w;  w += (size_t)NWT * Dc * Dc * sizeof(short);
    short* WTf1    = (short*)w;  w += (size_t)224 * 224 * sizeof(short);
    short* inb     = (short*)w;  w += (size_t)4 * NPc * Dc * sizeof(short);
    short* vt      = (short*)w;  w += (size_t)2 * 256 * 64 * 224 * sizeof(short);
    short* ctxb    = (short*)w;  w += (size_t)NPc * Dc * sizeof(short);
    short* ctxcb   = (short*)w;  w += (size_t)NPc * Dc * sizeof(short);

    // input-tensor id per projection: 0=X 1=AT 2=P 3=HA
    const int aid[NPROJ] = {0,0,0,2,2,1,1,3,3,3,0,1,1,3,2};
    const float* Wmat[NWT] = {Wq, Wk, Wv, Wqp, Wkp, Waq, Wak, Waq, Wak, Wav,
                              Wqic, Wqci, Wqcp, Wqcp, Wqpc, Wd, Wda};
    const float* bmat[NPROJ] = {bq, bk, bv, bqp, bkp, baq, bak, baq, bak, bav,
                                bqic, bqci, bqcp, bqcp, bqpc};

    ProjArgsM pm;
    WList wl;
    for (int i = 0; i < NPROJ; i++) {
        pm.A[i]    = inb + (size_t)aid[i] * NPc * Dc;
        pm.bias[i] = bmat[i];
    }
    for (int i = 0; i < NWT; i++) wl.w[i] = Wmat[i];

    // 0. prep (casts + weight transposes), one launch
    prep_kernel<<<13268, 256, 0, stream>>>(X, AT, P, HA, inb, wl, WTall, Wf1, WTf1);

    // 1. projections (MFMA, bf16 in/out, pipelined B loads, coalesced epilogue)
    proj_mfma<<<dim3(NPc / 64, NPROJ), 256, 0, stream>>>(pm, WTall, proj_bf);

    // 1b. V transpose (iv, hav) -> vt bf16
    vt_kernel<<<512, 256, 0, stream>>>(proj_bf, vt);

    // 2. merged fused attention (256 threads, ctx out in bf16)
    fused12<<<12800, 256, 0, stream>>>(proj_bf, vt, fw, fwc, mask, WTf1, bf1, Wf2, ctxb, ctxcb);

    // 3. output projections + residual + LayerNorm (MFMA, pipelined), one launch
    out_ln2<<<800, 256, 0, stream>>>(ctxb, ctxcb,
                                     WTall + (size_t)15 * Dc * Dc,
                                     WTall + (size_t)16 * Dc * Dc,
                                     bd, bda, X, HA,
                                     ln_g, ln_b, lna_g, lna_b,
                                     (float*)d_out, (float*)d_out + (size_t)NPc * Dc);
}